// Round 1
// baseline (1332.585 us; speedup 1.0000x reference)
//
#include <hip/hip_runtime.h>

#define NN 50000
#define NE 400000
#define NH 4
#define NTY 3
#define ETY 4
#define EDIM 32
// Both layers: K = 256 input dim, 256 = HEADS*C output dim (C=64)

// ---------------------------------------------------------------- prep: fold
// u[tn][t][h][d] = sum_c W_dst[tn][d][h*64+c] * att_dst[t][h][c]   (12288 each)
// v[t][h][d]     = sum_c W_edge[t][d][h*64+c] * att_edge[t][h][c]  (512 each)
__global__ __launch_bounds__(256) void prep_fold(
    const float* __restrict__ W_dst1, const float* __restrict__ att_dst1,
    const float* __restrict__ W_edge1, const float* __restrict__ att_edge1,
    const float* __restrict__ W_dst2, const float* __restrict__ att_dst2,
    const float* __restrict__ W_edge2, const float* __restrict__ att_edge2,
    float* __restrict__ u1, float* __restrict__ u2,
    float* __restrict__ v1, float* __restrict__ v2)
{
    int idx = blockIdx.x * 256 + threadIdx.x;   // 25600 total
    if (idx < 24576) {
        const float* W; const float* A; float* U; int i;
        if (idx < 12288) { W = W_dst1; A = att_dst1; U = u1; i = idx; }
        else             { W = W_dst2; A = att_dst2; U = u2; i = idx - 12288; }
        int d = i & 255, h = (i >> 8) & 3, t = (i >> 10) & 3, tn = i >> 12;
        const float* wp = W + tn * 65536 + d * 256 + h * 64;
        const float* ap = A + t * 256 + h * 64;
        float s = 0.f;
        #pragma unroll 8
        for (int c = 0; c < 64; ++c) s += wp[c] * ap[c];
        U[(tn * 16 + t * 4 + h) * 256 + d] = s;
    } else {
        int i = idx - 24576;
        const float* W; const float* A; float* V;
        if (i < 512) { W = W_edge1; A = att_edge1; V = v1; }
        else         { W = W_edge2; A = att_edge2; V = v2; i -= 512; }
        int d = i & 31, h = (i >> 5) & 3, t = i >> 7;
        const float* wp = W + t * (EDIM * 256) + d * 256 + h * 64;
        const float* ap = A + t * 256 + h * 64;
        float s = 0.f;
        #pragma unroll 8
        for (int c = 0; c < 64; ++c) s += wp[c] * ap[c];
        V[(t * 4 + h) * 32 + d] = s;
    }
}

// ---------------------------------------------------------------- CSR build
__global__ void hist_k(const int* __restrict__ dst, const int* __restrict__ ntype,
                       int* __restrict__ cnt, int* __restrict__ ntcnt)
{
    int i = blockIdx.x * 256 + threadIdx.x;
    if (i < NE) atomicAdd(&cnt[dst[i]], 1);
    if (i < NN) atomicAdd(&ntcnt[ntype[i]], 1);
}

__global__ __launch_bounds__(1024) void scan_k(const int* __restrict__ cnt,
                                               int* __restrict__ row_ptr,
                                               const int* __restrict__ ntcnt,
                                               int* __restrict__ ntoff)
{
    __shared__ int part[1024];
    const int CHK = 49;                    // 1024*49 = 50176 >= 50000
    int tid = threadIdx.x;
    int b0 = tid * CHK;
    int s = 0;
    for (int i = 0; i < CHK; ++i) { int j = b0 + i; if (j < NN) s += cnt[j]; }
    part[tid] = s;
    __syncthreads();
    for (int off = 1; off < 1024; off <<= 1) {
        int v = (tid >= off) ? part[tid - off] : 0;
        __syncthreads();
        part[tid] += v;
        __syncthreads();
    }
    int run = part[tid] - s;               // exclusive prefix
    for (int i = 0; i < CHK; ++i) {
        int j = b0 + i;
        if (j < NN) { row_ptr[j] = run; run += cnt[j]; }
    }
    if (tid == 1023) row_ptr[NN] = part[1023];
    if (tid == 0) {
        ntoff[0] = 0;
        ntoff[1] = ntcnt[0];
        ntoff[2] = ntcnt[0] + ntcnt[1];
        ntoff[3] = ntcnt[0] + ntcnt[1] + ntcnt[2];
    }
}

__global__ void scatter_k(const int* __restrict__ dst, const int* __restrict__ ntype,
                          const int* __restrict__ row_ptr, int* __restrict__ cursor,
                          int* __restrict__ perm,
                          const int* __restrict__ ntoff, int* __restrict__ ntcur,
                          int* __restrict__ node_perm)
{
    int i = blockIdx.x * 256 + threadIdx.x;
    if (i < NE) {
        int d = dst[i];
        int pos = row_ptr[d] + atomicAdd(&cursor[d], 1);
        perm[pos] = i;
    }
    if (i < NN) {
        int t = ntype[i];
        int pos = ntoff[t] + atomicAdd(&ntcur[t], 1);
        node_perm[pos] = i;
    }
}

// ---------------------------------------------------------------- GEMM
// Row-gathered tiled SGEMM: rows bucketed by node type (blockIdx.z = type).
// xout[node_perm[r], :] = xin[node_perm[r], :] @ W[type]   (K=256, N=256)
#define TM 64
#define TN 64
#define TK 16
__global__ __launch_bounds__(256) void gemm_rows(
    const float* __restrict__ xin, const float* __restrict__ Wall,
    const int* __restrict__ node_perm, const int* __restrict__ ntoff,
    float* __restrict__ xout)
{
    int t = blockIdx.z;
    int seg0 = ntoff[t], seg1 = ntoff[t + 1];
    int row0 = seg0 + blockIdx.x * TM;
    if (row0 >= seg1) return;
    int col0 = blockIdx.y * TN;
    const float* W = Wall + (size_t)t * 256 * 256;

    __shared__ int rows[TM];
    __shared__ __align__(16) float At[TK][TM + 4];  // transposed A tile
    __shared__ __align__(16) float Bt[TK][TN];

    int tid = threadIdx.x;
    if (tid < TM) {
        int rp = row0 + tid;
        rows[tid] = (rp < seg1) ? node_perm[rp] : -1;
    }
    __syncthreads();

    int ty = tid >> 4, tx = tid & 15;      // micro-tile 4x4
    int lr = tid >> 2, lc4 = (tid & 3) * 4;       // A-load mapping
    int bk = tid >> 4, bc4 = (tid & 15) * 4;      // B-load mapping

    int grA = rows[lr];
    const float* arow = xin + (size_t)(grA < 0 ? 0 : grA) * 256;

    float acc[4][4] = {};

    for (int k0 = 0; k0 < 256; k0 += TK) {
        float4 av = make_float4(0.f, 0.f, 0.f, 0.f);
        if (grA >= 0) av = *(const float4*)(arow + k0 + lc4);
        At[lc4 + 0][lr] = av.x; At[lc4 + 1][lr] = av.y;
        At[lc4 + 2][lr] = av.z; At[lc4 + 3][lr] = av.w;
        float4 bv = *(const float4*)(W + (size_t)(k0 + bk) * 256 + col0 + bc4);
        *(float4*)&Bt[bk][bc4] = bv;
        __syncthreads();
        #pragma unroll
        for (int k = 0; k < TK; ++k) {
            float4 a = *(const float4*)&At[k][ty * 4];
            float4 b = *(const float4*)&Bt[k][tx * 4];
            acc[0][0] += a.x * b.x; acc[0][1] += a.x * b.y; acc[0][2] += a.x * b.z; acc[0][3] += a.x * b.w;
            acc[1][0] += a.y * b.x; acc[1][1] += a.y * b.y; acc[1][2] += a.y * b.z; acc[1][3] += a.y * b.w;
            acc[2][0] += a.z * b.x; acc[2][1] += a.z * b.y; acc[2][2] += a.z * b.z; acc[2][3] += a.z * b.w;
            acc[3][0] += a.w * b.x; acc[3][1] += a.w * b.y; acc[3][2] += a.w * b.z; acc[3][3] += a.w * b.w;
        }
        __syncthreads();
    }
    #pragma unroll
    for (int i = 0; i < 4; ++i) {
        int gr = rows[ty * 4 + i];
        if (gr >= 0) {
            float4 o = make_float4(acc[i][0], acc[i][1], acc[i][2], acc[i][3]);
            *(float4*)(xout + (size_t)gr * 256 + col0 + tx * 4) = o;
        }
    }
}

// ---------------------------------------------------------------- scores
// s_src[n,t,h] = sum_c x_src[n,h,c]*att_src[t,h,c]
// s_dst[n,t,h] = sum_d xin[n,d]*u[tn,t,h,d]
__global__ __launch_bounds__(256) void scores_k(
    const float* __restrict__ x_src, const float* __restrict__ xin,
    const float* __restrict__ att_src, const float* __restrict__ u,
    const int* __restrict__ ntype,
    float* __restrict__ s_src, float* __restrict__ s_dst)
{
    int n = blockIdx.x * 4 + (threadIdx.x >> 6);
    int lane = threadIdx.x & 63;
    float4 xs = *(const float4*)(x_src + (size_t)n * 256 + lane * 4);
    float4 xi = *(const float4*)(xin + (size_t)n * 256 + lane * 4);
    int tn = ntype[n];
    int h = lane >> 4;
    #pragma unroll
    for (int t = 0; t < 4; ++t) {
        float4 a = *(const float4*)(att_src + t * 256 + lane * 4);
        float p = xs.x * a.x + xs.y * a.y + xs.z * a.z + xs.w * a.w;
        p += __shfl_xor(p, 1); p += __shfl_xor(p, 2);
        p += __shfl_xor(p, 4); p += __shfl_xor(p, 8);
        if ((lane & 15) == 0) s_src[(size_t)n * 16 + t * 4 + h] = p;
    }
    #pragma unroll
    for (int th = 0; th < 16; ++th) {
        float4 uu = *(const float4*)(u + (size_t)(tn * 16 + th) * 256 + lane * 4);
        float p = xi.x * uu.x + xi.y * uu.y + xi.z * uu.z + xi.w * uu.w;
        p += __shfl_xor(p, 1); p += __shfl_xor(p, 2); p += __shfl_xor(p, 4);
        p += __shfl_xor(p, 8); p += __shfl_xor(p, 16); p += __shfl_xor(p, 32);
        if (lane == 0) s_dst[(size_t)n * 16 + th] = p;
    }
}

// ---------------------------------------------------------------- edge scores
__global__ void sedge_k(const float* __restrict__ eattr, const int* __restrict__ etype,
                        const float* __restrict__ v, float* __restrict__ sedge)
{
    int e = blockIdx.x * 256 + threadIdx.x;
    if (e >= NE) return;
    int t = etype[e];
    float4 ea[8];
    #pragma unroll
    for (int i = 0; i < 8; ++i) ea[i] = *(const float4*)(eattr + (size_t)e * 32 + i * 4);
    #pragma unroll
    for (int h = 0; h < 4; ++h) {
        const float* vp = v + (t * 4 + h) * 32;
        float s = 0.f;
        #pragma unroll
        for (int i = 0; i < 8; ++i) {
            float4 vv = *(const float4*)(vp + i * 4);
            s += ea[i].x * vv.x + ea[i].y * vv.y + ea[i].z * vv.z + ea[i].w * vv.w;
        }
        sedge[(size_t)e * 4 + h] = s;
    }
}

// ---------------------------------------------------------------- aggregate
// One wave per dst node: single-pass online softmax over its CSR edges,
// gathering x_src[src] rows. Fused epilogue:
//   mode 1: +bias, LayerNorm, ELU  -> h (N,256)
//   mode 2: mean over heads +bias  -> out (N,64)
__global__ __launch_bounds__(256) void aggregate_k(
    const float* __restrict__ x_src, const float* __restrict__ s_src,
    const float* __restrict__ s_dst, const float* __restrict__ sedge,
    const int* __restrict__ row_ptr, const int* __restrict__ perm,
    const int* __restrict__ srca, const int* __restrict__ etype,
    const float* __restrict__ bias, const float* __restrict__ gamma,
    const float* __restrict__ beta, float* __restrict__ out, int mode)
{
    int n = blockIdx.x * 4 + (threadIdx.x >> 6);
    int lane = threadIdx.x & 63;
    int h2 = lane >> 4;                    // head owned by this lane's channels
    int beg = row_ptr[n], end = row_ptr[n + 1];

    float sd0 = s_dst[(size_t)n * 16 + 0 * 4 + h2];
    float sd1 = s_dst[(size_t)n * 16 + 1 * 4 + h2];
    float sd2 = s_dst[(size_t)n * 16 + 2 * 4 + h2];
    float sd3 = s_dst[(size_t)n * 16 + 3 * 4 + h2];

    float m = -1e30f, den = 0.f;
    float4 acc = make_float4(0.f, 0.f, 0.f, 0.f);
    for (int i = beg; i < end; ++i) {
        int e = perm[i];
        int s = srca[e];
        int t = etype[e];
        float sdv = (t == 0) ? sd0 : (t == 1) ? sd1 : (t == 2) ? sd2 : sd3;
        float a = s_src[(size_t)s * 16 + t * 4 + h2] + sdv + sedge[(size_t)e * 4 + h2];
        a = (a >= 0.f) ? a : 0.2f * a;     // LeakyReLU
        float mn = fmaxf(m, a);
        float sc = __expf(m - mn);         // first iter: exp(-1e30) = 0
        float ae = __expf(a - mn);
        den = den * sc + ae;
        float4 xv = *(const float4*)(x_src + (size_t)s * 256 + lane * 4);
        acc.x = acc.x * sc + xv.x * ae;
        acc.y = acc.y * sc + xv.y * ae;
        acc.z = acc.z * sc + xv.z * ae;
        acc.w = acc.w * sc + xv.w * ae;
        m = mn;
    }
    float inv = 1.f / (den + 1e-16f);
    acc.x *= inv; acc.y *= inv; acc.z *= inv; acc.w *= inv;

    if (mode == 1) {
        float4 bb = *(const float4*)(bias + lane * 4);
        float vals[4] = { acc.x + bb.x, acc.y + bb.y, acc.z + bb.z, acc.w + bb.w };
        float s = vals[0] + vals[1] + vals[2] + vals[3];
        s += __shfl_xor(s, 1); s += __shfl_xor(s, 2); s += __shfl_xor(s, 4);
        s += __shfl_xor(s, 8); s += __shfl_xor(s, 16); s += __shfl_xor(s, 32);
        float mu = s * (1.f / 256.f);
        float q = 0.f;
        #pragma unroll
        for (int j = 0; j < 4; ++j) { float d = vals[j] - mu; q += d * d; }
        q += __shfl_xor(q, 1); q += __shfl_xor(q, 2); q += __shfl_xor(q, 4);
        q += __shfl_xor(q, 8); q += __shfl_xor(q, 16); q += __shfl_xor(q, 32);
        float r = rsqrtf(q * (1.f / 256.f) + 1e-5f);
        float4 gg = *(const float4*)(gamma + lane * 4);
        float4 be = *(const float4*)(beta + lane * 4);
        float4 o;
        float y;
        y = (vals[0] - mu) * r * gg.x + be.x; o.x = (y > 0.f) ? y : (__expf(y) - 1.f);
        y = (vals[1] - mu) * r * gg.y + be.y; o.y = (y > 0.f) ? y : (__expf(y) - 1.f);
        y = (vals[2] - mu) * r * gg.z + be.z; o.z = (y > 0.f) ? y : (__expf(y) - 1.f);
        y = (vals[3] - mu) * r * gg.w + be.w; o.w = (y > 0.f) ? y : (__expf(y) - 1.f);
        *(float4*)(out + (size_t)n * 256 + lane * 4) = o;
    } else {
        acc.x += __shfl_xor(acc.x, 16); acc.x += __shfl_xor(acc.x, 32);
        acc.y += __shfl_xor(acc.y, 16); acc.y += __shfl_xor(acc.y, 32);
        acc.z += __shfl_xor(acc.z, 16); acc.z += __shfl_xor(acc.z, 32);
        acc.w += __shfl_xor(acc.w, 16); acc.w += __shfl_xor(acc.w, 32);
        if (lane < 16) {
            float4 bb = *(const float4*)(bias + lane * 4);
            float4 o;
            o.x = acc.x * 0.25f + bb.x;
            o.y = acc.y * 0.25f + bb.y;
            o.z = acc.z * 0.25f + bb.z;
            o.w = acc.w * 0.25f + bb.w;
            *(float4*)(out + (size_t)n * 64 + lane * 4) = o;
        }
    }
}

// ---------------------------------------------------------------- launch
extern "C" void kernel_launch(void* const* d_in, const int* in_sizes, int n_in,
                              void* d_out, int out_size, void* d_ws, size_t ws_size,
                              hipStream_t stream)
{
    (void)in_sizes; (void)n_in; (void)out_size;
    const float* x        = (const float*)d_in[0];
    const int*   ei       = (const int*)d_in[1];
    const int*   ntype    = (const int*)d_in[2];
    const int*   etype    = (const int*)d_in[3];
    const float* eattr    = (const float*)d_in[4];
    const float* W_src1   = (const float*)d_in[5];
    const float* W_dst1   = (const float*)d_in[6];
    const float* att_src1 = (const float*)d_in[7];
    const float* att_dst1 = (const float*)d_in[8];
    const float* W_edge1  = (const float*)d_in[9];
    const float* att_edge1= (const float*)d_in[10];
    const float* bias1    = (const float*)d_in[11];
    const float* gamma1   = (const float*)d_in[12];
    const float* beta1    = (const float*)d_in[13];
    const float* W_src2   = (const float*)d_in[14];
    // d_in[15] = W_dst2 (used only via fold), d_in[16..19] below
    const float* W_dst2   = (const float*)d_in[15];
    const float* att_src2 = (const float*)d_in[16];
    const float* att_dst2 = (const float*)d_in[17];
    const float* W_edge2  = (const float*)d_in[18];
    const float* att_edge2= (const float*)d_in[19];
    const float* bias2    = (const float*)d_in[20];

    char* w = (char*)d_ws;
    size_t off = 0;
    auto carve = [&](size_t bytes) -> char* {
        char* p = w + off;
        off = (off + bytes + 255) & ~(size_t)255;
        return p;
    };
    float* x_src    = (float*)carve((size_t)NN * 256 * 4);
    float* hbuf     = (float*)carve((size_t)NN * 256 * 4);
    float* s_src    = (float*)carve((size_t)NN * 16 * 4);
    float* s_dst    = (float*)carve((size_t)NN * 16 * 4);
    float* sedge    = (float*)carve((size_t)NE * 4 * 4);
    int*   cnt      = (int*)carve((size_t)(2 * NN + 8) * 4);
    int*   cursor   = cnt + NN;
    int*   ntcnt    = cnt + 2 * NN;
    int*   ntcur    = ntcnt + 4;
    int*   row_ptr  = (int*)carve((size_t)(NN + 1) * 4);
    int*   perm     = (int*)carve((size_t)NE * 4);
    int*   node_perm= (int*)carve((size_t)NN * 4);
    int*   ntoff    = (int*)carve(4 * 4);
    float* u1       = (float*)carve(12288 * 4);
    float* u2       = (float*)carve(12288 * 4);
    float* v1       = (float*)carve(512 * 4);
    float* v2       = (float*)carve(512 * 4);
    if (off > ws_size) return;  // workspace too small; bail without corrupting

    const int* srca = ei;
    const int* dsta = ei + NE;

    hipMemsetAsync(cnt, 0, (size_t)(2 * NN + 8) * 4, stream);

    prep_fold<<<100, 256, 0, stream>>>(W_dst1, att_dst1, W_edge1, att_edge1,
                                       W_dst2, att_dst2, W_edge2, att_edge2,
                                       u1, u2, v1, v2);
    hist_k<<<(NE + 255) / 256, 256, 0, stream>>>(dsta, ntype, cnt, ntcnt);
    scan_k<<<1, 1024, 0, stream>>>(cnt, row_ptr, ntcnt, ntoff);
    scatter_k<<<(NE + 255) / 256, 256, 0, stream>>>(dsta, ntype, row_ptr, cursor,
                                                    perm, ntoff, ntcur, node_perm);

    dim3 ggrid((NN + TM - 1) / TM, 256 / TN, NTY);

    // ---- layer 1
    gemm_rows<<<ggrid, 256, 0, stream>>>(x, W_src1, node_perm, ntoff, x_src);
    scores_k<<<NN / 4, 256, 0, stream>>>(x_src, x, att_src1, u1, ntype, s_src, s_dst);
    sedge_k<<<(NE + 255) / 256, 256, 0, stream>>>(eattr, etype, v1, sedge);
    aggregate_k<<<NN / 4, 256, 0, stream>>>(x_src, s_src, s_dst, sedge, row_ptr, perm,
                                            srca, etype, bias1, gamma1, beta1, hbuf, 1);

    // ---- layer 2
    gemm_rows<<<ggrid, 256, 0, stream>>>(hbuf, W_src2, node_perm, ntoff, x_src);
    scores_k<<<NN / 4, 256, 0, stream>>>(x_src, hbuf, att_src2, u2, ntype, s_src, s_dst);
    sedge_k<<<(NE + 255) / 256, 256, 0, stream>>>(eattr, etype, v2, sedge);
    aggregate_k<<<NN / 4, 256, 0, stream>>>(x_src, s_src, s_dst, sedge, row_ptr, perm,
                                            srca, etype, bias2, nullptr, nullptr,
                                            (float*)d_out, 2);
}

// Round 2
// 809.056 us; speedup vs baseline: 1.6471x; 1.6471x over previous
//
#include <hip/hip_runtime.h>

#define NN 50000
#define NE 400000
#define NH 4
#define NTY 3
#define ETY 4
#define EDIM 32
// Both layers: K = 256 input dim, 256 = HEADS*C output dim (C=64)

// ---------------------------------------------------------------- prep: fold
// u[tn][t][h][d] = sum_c W_dst[tn][d][h*64+c] * att_dst[t][h][c]   (12288 each)
// v[t][h][d]     = sum_c W_edge[t][d][h*64+c] * att_edge[t][h][c]  (512 each)
__global__ __launch_bounds__(256) void prep_fold(
    const float* __restrict__ W_dst1, const float* __restrict__ att_dst1,
    const float* __restrict__ W_edge1, const float* __restrict__ att_edge1,
    const float* __restrict__ W_dst2, const float* __restrict__ att_dst2,
    const float* __restrict__ W_edge2, const float* __restrict__ att_edge2,
    float* __restrict__ u1, float* __restrict__ u2,
    float* __restrict__ v1, float* __restrict__ v2)
{
    int idx = blockIdx.x * 256 + threadIdx.x;   // 25600 total
    if (idx < 24576) {
        const float* W; const float* A; float* U; int i;
        if (idx < 12288) { W = W_dst1; A = att_dst1; U = u1; i = idx; }
        else             { W = W_dst2; A = att_dst2; U = u2; i = idx - 12288; }
        int d = i & 255, h = (i >> 8) & 3, t = (i >> 10) & 3, tn = i >> 12;
        const float* wp = W + tn * 65536 + d * 256 + h * 64;
        const float* ap = A + t * 256 + h * 64;
        float s = 0.f;
        #pragma unroll 8
        for (int c = 0; c < 64; ++c) s += wp[c] * ap[c];
        U[(tn * 16 + t * 4 + h) * 256 + d] = s;
    } else {
        int i = idx - 24576;
        const float* W; const float* A; float* V;
        if (i < 512) { W = W_edge1; A = att_edge1; V = v1; }
        else         { W = W_edge2; A = att_edge2; V = v2; i -= 512; }
        int d = i & 31, h = (i >> 5) & 3, t = i >> 7;
        const float* wp = W + t * (EDIM * 256) + d * 256 + h * 64;
        const float* ap = A + t * 256 + h * 64;
        float s = 0.f;
        #pragma unroll 8
        for (int c = 0; c < 64; ++c) s += wp[c] * ap[c];
        V[(t * 4 + h) * 32 + d] = s;
    }
}

// ---------------------------------------------------------------- CSR build
// Per-edge histogram only (50K distinct counters -> low contention).
__global__ void hist_k(const int* __restrict__ dst, int* __restrict__ cnt)
{
    int i = blockIdx.x * 256 + threadIdx.x;
    if (i < NE) atomicAdd(&cnt[dst[i]], 1);
}

// Single block: edge-count scan -> row_ptr, AND deterministic counting sort
// of nodes by type (3 buckets) -> node_perm, ntoff. No contended atomics.
__global__ __launch_bounds__(1024) void scan_k(const int* __restrict__ cnt,
                                               int* __restrict__ row_ptr,
                                               const int* __restrict__ ntype,
                                               int* __restrict__ ntoff,
                                               int* __restrict__ node_perm)
{
    __shared__ int part[1024];
    __shared__ int tp0[1024], tp1[1024], tp2[1024];
    const int CHK = 49;                    // 1024*49 = 50176 >= 50000
    int tid = threadIdx.x;
    int b0 = tid * CHK;

    int s = 0, c0 = 0, c1 = 0, c2 = 0;
    for (int i = 0; i < CHK; ++i) {
        int j = b0 + i;
        if (j < NN) {
            s += cnt[j];
            int t = ntype[j];
            c0 += (t == 0); c1 += (t == 1); c2 += (t == 2);
        }
    }
    part[tid] = s; tp0[tid] = c0; tp1[tid] = c1; tp2[tid] = c2;
    __syncthreads();
    for (int off = 1; off < 1024; off <<= 1) {
        int v  = (tid >= off) ? part[tid - off] : 0;
        int v0 = (tid >= off) ? tp0[tid - off] : 0;
        int v1 = (tid >= off) ? tp1[tid - off] : 0;
        int v2 = (tid >= off) ? tp2[tid - off] : 0;
        __syncthreads();
        part[tid] += v; tp0[tid] += v0; tp1[tid] += v1; tp2[tid] += v2;
        __syncthreads();
    }
    int T0 = tp0[1023], T1 = tp1[1023];

    // row_ptr
    int run = part[tid] - s;               // exclusive prefix
    for (int i = 0; i < CHK; ++i) {
        int j = b0 + i;
        if (j < NN) { row_ptr[j] = run; run += cnt[j]; }
    }
    if (tid == 1023) row_ptr[NN] = part[1023];

    // node counting sort (stable, deterministic)
    int r0 = tp0[tid] - c0;
    int r1 = T0 + (tp1[tid] - c1);
    int r2 = T0 + T1 + (tp2[tid] - c2);
    for (int i = 0; i < CHK; ++i) {
        int j = b0 + i;
        if (j < NN) {
            int t = ntype[j];
            int pos = (t == 0) ? r0++ : (t == 1) ? r1++ : r2++;
            node_perm[pos] = j;
        }
    }
    if (tid == 0) {
        int T2 = tp2[1023];
        ntoff[0] = 0; ntoff[1] = T0; ntoff[2] = T0 + T1; ntoff[3] = T0 + T1 + T2;
    }
}

__global__ void scatter_k(const int* __restrict__ dst,
                          const int* __restrict__ row_ptr, int* __restrict__ cursor,
                          int* __restrict__ perm)
{
    int i = blockIdx.x * 256 + threadIdx.x;
    if (i < NE) {
        int d = dst[i];
        int pos = row_ptr[d] + atomicAdd(&cursor[d], 1);
        perm[pos] = i;
    }
}

// ---------------------------------------------------------------- GEMM
// Row-gathered tiled SGEMM: rows bucketed by node type (blockIdx.z = type).
// xout[node_perm[r], :] = xin[node_perm[r], :] @ W[type]   (K=256, N=256)
#define TM 64
#define TN 64
#define TK 16
__global__ __launch_bounds__(256) void gemm_rows(
    const float* __restrict__ xin, const float* __restrict__ Wall,
    const int* __restrict__ node_perm, const int* __restrict__ ntoff,
    float* __restrict__ xout)
{
    int t = blockIdx.z;
    int seg0 = ntoff[t], seg1 = ntoff[t + 1];
    int row0 = seg0 + blockIdx.x * TM;
    if (row0 >= seg1) return;
    int col0 = blockIdx.y * TN;
    const float* W = Wall + (size_t)t * 256 * 256;

    __shared__ int rows[TM];
    __shared__ __align__(16) float At[TK][TM + 4];  // transposed A tile
    __shared__ __align__(16) float Bt[TK][TN];

    int tid = threadIdx.x;
    if (tid < TM) {
        int rp = row0 + tid;
        rows[tid] = (rp < seg1) ? node_perm[rp] : -1;
    }
    __syncthreads();

    int ty = tid >> 4, tx = tid & 15;      // micro-tile 4x4
    int lr = tid >> 2, lc4 = (tid & 3) * 4;       // A-load mapping
    int bk = tid >> 4, bc4 = (tid & 15) * 4;      // B-load mapping

    int grA = rows[lr];
    const float* arow = xin + (size_t)(grA < 0 ? 0 : grA) * 256;

    float acc[4][4] = {};

    for (int k0 = 0; k0 < 256; k0 += TK) {
        float4 av = make_float4(0.f, 0.f, 0.f, 0.f);
        if (grA >= 0) av = *(const float4*)(arow + k0 + lc4);
        At[lc4 + 0][lr] = av.x; At[lc4 + 1][lr] = av.y;
        At[lc4 + 2][lr] = av.z; At[lc4 + 3][lr] = av.w;
        float4 bv = *(const float4*)(W + (size_t)(k0 + bk) * 256 + col0 + bc4);
        *(float4*)&Bt[bk][bc4] = bv;
        __syncthreads();
        #pragma unroll
        for (int k = 0; k < TK; ++k) {
            float4 a = *(const float4*)&At[k][ty * 4];
            float4 b = *(const float4*)&Bt[k][tx * 4];
            acc[0][0] += a.x * b.x; acc[0][1] += a.x * b.y; acc[0][2] += a.x * b.z; acc[0][3] += a.x * b.w;
            acc[1][0] += a.y * b.x; acc[1][1] += a.y * b.y; acc[1][2] += a.y * b.z; acc[1][3] += a.y * b.w;
            acc[2][0] += a.z * b.x; acc[2][1] += a.z * b.y; acc[2][2] += a.z * b.z; acc[2][3] += a.z * b.w;
            acc[3][0] += a.w * b.x; acc[3][1] += a.w * b.y; acc[3][2] += a.w * b.z; acc[3][3] += a.w * b.w;
        }
        __syncthreads();
    }
    #pragma unroll
    for (int i = 0; i < 4; ++i) {
        int gr = rows[ty * 4 + i];
        if (gr >= 0) {
            float4 o = make_float4(acc[i][0], acc[i][1], acc[i][2], acc[i][3]);
            *(float4*)(xout + (size_t)gr * 256 + col0 + tx * 4) = o;
        }
    }
}

// ---------------------------------------------------------------- scores
// s_src[n,t,h] = sum_c x_src[n,h,c]*att_src[t,h,c]
// s_dst[n,t,h] = sum_d xin[n,d]*u[tn,t,h,d]
__global__ __launch_bounds__(256) void scores_k(
    const float* __restrict__ x_src, const float* __restrict__ xin,
    const float* __restrict__ att_src, const float* __restrict__ u,
    const int* __restrict__ ntype,
    float* __restrict__ s_src, float* __restrict__ s_dst)
{
    int n = blockIdx.x * 4 + (threadIdx.x >> 6);
    int lane = threadIdx.x & 63;
    float4 xs = *(const float4*)(x_src + (size_t)n * 256 + lane * 4);
    float4 xi = *(const float4*)(xin + (size_t)n * 256 + lane * 4);
    int tn = ntype[n];
    int h = lane >> 4;
    #pragma unroll
    for (int t = 0; t < 4; ++t) {
        float4 a = *(const float4*)(att_src + t * 256 + lane * 4);
        float p = xs.x * a.x + xs.y * a.y + xs.z * a.z + xs.w * a.w;
        p += __shfl_xor(p, 1); p += __shfl_xor(p, 2);
        p += __shfl_xor(p, 4); p += __shfl_xor(p, 8);
        if ((lane & 15) == 0) s_src[(size_t)n * 16 + t * 4 + h] = p;
    }
    #pragma unroll
    for (int th = 0; th < 16; ++th) {
        float4 uu = *(const float4*)(u + (size_t)(tn * 16 + th) * 256 + lane * 4);
        float p = xi.x * uu.x + xi.y * uu.y + xi.z * uu.z + xi.w * uu.w;
        p += __shfl_xor(p, 1); p += __shfl_xor(p, 2); p += __shfl_xor(p, 4);
        p += __shfl_xor(p, 8); p += __shfl_xor(p, 16); p += __shfl_xor(p, 32);
        if (lane == 0) s_dst[(size_t)n * 16 + th] = p;
    }
}

// ---------------------------------------------------------------- edge scores
__global__ void sedge_k(const float* __restrict__ eattr, const int* __restrict__ etype,
                        const float* __restrict__ v, float* __restrict__ sedge)
{
    int e = blockIdx.x * 256 + threadIdx.x;
    if (e >= NE) return;
    int t = etype[e];
    float4 ea[8];
    #pragma unroll
    for (int i = 0; i < 8; ++i) ea[i] = *(const float4*)(eattr + (size_t)e * 32 + i * 4);
    #pragma unroll
    for (int h = 0; h < 4; ++h) {
        const float* vp = v + (t * 4 + h) * 32;
        float s = 0.f;
        #pragma unroll
        for (int i = 0; i < 8; ++i) {
            float4 vv = *(const float4*)(vp + i * 4);
            s += ea[i].x * vv.x + ea[i].y * vv.y + ea[i].z * vv.z + ea[i].w * vv.w;
        }
        sedge[(size_t)e * 4 + h] = s;
    }
}

// ---------------------------------------------------------------- aggregate
// One wave per dst node: single-pass online softmax over its CSR edges,
// gathering x_src[src] rows. Fused epilogue:
//   mode 1: +bias, LayerNorm, ELU  -> h (N,256)
//   mode 2: mean over heads +bias  -> out (N,64)
__global__ __launch_bounds__(256) void aggregate_k(
    const float* __restrict__ x_src, const float* __restrict__ s_src,
    const float* __restrict__ s_dst, const float* __restrict__ sedge,
    const int* __restrict__ row_ptr, const int* __restrict__ perm,
    const int* __restrict__ srca, const int* __restrict__ etype,
    const float* __restrict__ bias, const float* __restrict__ gamma,
    const float* __restrict__ beta, float* __restrict__ out, int mode)
{
    int n = blockIdx.x * 4 + (threadIdx.x >> 6);
    int lane = threadIdx.x & 63;
    int h2 = lane >> 4;                    // head owned by this lane's channels
    int beg = row_ptr[n], end = row_ptr[n + 1];

    float sd0 = s_dst[(size_t)n * 16 + 0 * 4 + h2];
    float sd1 = s_dst[(size_t)n * 16 + 1 * 4 + h2];
    float sd2 = s_dst[(size_t)n * 16 + 2 * 4 + h2];
    float sd3 = s_dst[(size_t)n * 16 + 3 * 4 + h2];

    float m = -1e30f, den = 0.f;
    float4 acc = make_float4(0.f, 0.f, 0.f, 0.f);
    for (int i = beg; i < end; ++i) {
        int e = perm[i];
        int s = srca[e];
        int t = etype[e];
        float sdv = (t == 0) ? sd0 : (t == 1) ? sd1 : (t == 2) ? sd2 : sd3;
        float a = s_src[(size_t)s * 16 + t * 4 + h2] + sdv + sedge[(size_t)e * 4 + h2];
        a = (a >= 0.f) ? a : 0.2f * a;     // LeakyReLU
        float mn = fmaxf(m, a);
        float sc = __expf(m - mn);         // first iter: exp(-1e30) = 0
        float ae = __expf(a - mn);
        den = den * sc + ae;
        float4 xv = *(const float4*)(x_src + (size_t)s * 256 + lane * 4);
        acc.x = acc.x * sc + xv.x * ae;
        acc.y = acc.y * sc + xv.y * ae;
        acc.z = acc.z * sc + xv.z * ae;
        acc.w = acc.w * sc + xv.w * ae;
        m = mn;
    }
    float inv = 1.f / (den + 1e-16f);
    acc.x *= inv; acc.y *= inv; acc.z *= inv; acc.w *= inv;

    if (mode == 1) {
        float4 bb = *(const float4*)(bias + lane * 4);
        float vals[4] = { acc.x + bb.x, acc.y + bb.y, acc.z + bb.z, acc.w + bb.w };
        float s = vals[0] + vals[1] + vals[2] + vals[3];
        s += __shfl_xor(s, 1); s += __shfl_xor(s, 2); s += __shfl_xor(s, 4);
        s += __shfl_xor(s, 8); s += __shfl_xor(s, 16); s += __shfl_xor(s, 32);
        float mu = s * (1.f / 256.f);
        float q = 0.f;
        #pragma unroll
        for (int j = 0; j < 4; ++j) { float d = vals[j] - mu; q += d * d; }
        q += __shfl_xor(q, 1); q += __shfl_xor(q, 2); q += __shfl_xor(q, 4);
        q += __shfl_xor(q, 8); q += __shfl_xor(q, 16); q += __shfl_xor(q, 32);
        float r = rsqrtf(q * (1.f / 256.f) + 1e-5f);
        float4 gg = *(const float4*)(gamma + lane * 4);
        float4 be = *(const float4*)(beta + lane * 4);
        float4 o;
        float y;
        y = (vals[0] - mu) * r * gg.x + be.x; o.x = (y > 0.f) ? y : (__expf(y) - 1.f);
        y = (vals[1] - mu) * r * gg.y + be.y; o.y = (y > 0.f) ? y : (__expf(y) - 1.f);
        y = (vals[2] - mu) * r * gg.z + be.z; o.z = (y > 0.f) ? y : (__expf(y) - 1.f);
        y = (vals[3] - mu) * r * gg.w + be.w; o.w = (y > 0.f) ? y : (__expf(y) - 1.f);
        *(float4*)(out + (size_t)n * 256 + lane * 4) = o;
    } else {
        acc.x += __shfl_xor(acc.x, 16); acc.x += __shfl_xor(acc.x, 32);
        acc.y += __shfl_xor(acc.y, 16); acc.y += __shfl_xor(acc.y, 32);
        acc.z += __shfl_xor(acc.z, 16); acc.z += __shfl_xor(acc.z, 32);
        acc.w += __shfl_xor(acc.w, 16); acc.w += __shfl_xor(acc.w, 32);
        if (lane < 16) {
            float4 bb = *(const float4*)(bias + lane * 4);
            float4 o;
            o.x = acc.x * 0.25f + bb.x;
            o.y = acc.y * 0.25f + bb.y;
            o.z = acc.z * 0.25f + bb.z;
            o.w = acc.w * 0.25f + bb.w;
            *(float4*)(out + (size_t)n * 64 + lane * 4) = o;
        }
    }
}

// ---------------------------------------------------------------- launch
extern "C" void kernel_launch(void* const* d_in, const int* in_sizes, int n_in,
                              void* d_out, int out_size, void* d_ws, size_t ws_size,
                              hipStream_t stream)
{
    (void)in_sizes; (void)n_in; (void)out_size;
    const float* x        = (const float*)d_in[0];
    const int*   ei       = (const int*)d_in[1];
    const int*   ntype    = (const int*)d_in[2];
    const int*   etype    = (const int*)d_in[3];
    const float* eattr    = (const float*)d_in[4];
    const float* W_src1   = (const float*)d_in[5];
    const float* W_dst1   = (const float*)d_in[6];
    const float* att_src1 = (const float*)d_in[7];
    const float* att_dst1 = (const float*)d_in[8];
    const float* W_edge1  = (const float*)d_in[9];
    const float* att_edge1= (const float*)d_in[10];
    const float* bias1    = (const float*)d_in[11];
    const float* gamma1   = (const float*)d_in[12];
    const float* beta1    = (const float*)d_in[13];
    const float* W_src2   = (const float*)d_in[14];
    const float* W_dst2   = (const float*)d_in[15];
    const float* att_src2 = (const float*)d_in[16];
    const float* att_dst2 = (const float*)d_in[17];
    const float* W_edge2  = (const float*)d_in[18];
    const float* att_edge2= (const float*)d_in[19];
    const float* bias2    = (const float*)d_in[20];

    char* w = (char*)d_ws;
    size_t off = 0;
    auto carve = [&](size_t bytes) -> char* {
        char* p = w + off;
        off = (off + bytes + 255) & ~(size_t)255;
        return p;
    };
    float* x_src    = (float*)carve((size_t)NN * 256 * 4);
    float* hbuf     = (float*)carve((size_t)NN * 256 * 4);
    float* s_src    = (float*)carve((size_t)NN * 16 * 4);
    float* s_dst    = (float*)carve((size_t)NN * 16 * 4);
    float* sedge    = (float*)carve((size_t)NE * 4 * 4);
    int*   cnt      = (int*)carve((size_t)(2 * NN) * 4);
    int*   cursor   = cnt + NN;
    int*   row_ptr  = (int*)carve((size_t)(NN + 1) * 4);
    int*   perm     = (int*)carve((size_t)NE * 4);
    int*   node_perm= (int*)carve((size_t)NN * 4);
    int*   ntoff    = (int*)carve(4 * 4);
    float* u1       = (float*)carve(12288 * 4);
    float* u2       = (float*)carve(12288 * 4);
    float* v1       = (float*)carve(512 * 4);
    float* v2       = (float*)carve(512 * 4);
    if (off > ws_size) return;  // workspace too small; bail without corrupting

    const int* srca = ei;
    const int* dsta = ei + NE;

    hipMemsetAsync(cnt, 0, (size_t)(2 * NN) * 4, stream);

    prep_fold<<<100, 256, 0, stream>>>(W_dst1, att_dst1, W_edge1, att_edge1,
                                       W_dst2, att_dst2, W_edge2, att_edge2,
                                       u1, u2, v1, v2);
    hist_k<<<(NE + 255) / 256, 256, 0, stream>>>(dsta, cnt);
    scan_k<<<1, 1024, 0, stream>>>(cnt, row_ptr, ntype, ntoff, node_perm);
    scatter_k<<<(NE + 255) / 256, 256, 0, stream>>>(dsta, row_ptr, cursor, perm);

    dim3 ggrid((NN + TM - 1) / TM, 256 / TN, NTY);

    // ---- layer 1
    gemm_rows<<<ggrid, 256, 0, stream>>>(x, W_src1, node_perm, ntoff, x_src);
    scores_k<<<NN / 4, 256, 0, stream>>>(x_src, x, att_src1, u1, ntype, s_src, s_dst);
    sedge_k<<<(NE + 255) / 256, 256, 0, stream>>>(eattr, etype, v1, sedge);
    aggregate_k<<<NN / 4, 256, 0, stream>>>(x_src, s_src, s_dst, sedge, row_ptr, perm,
                                            srca, etype, bias1, gamma1, beta1, hbuf, 1);

    // ---- layer 2
    gemm_rows<<<ggrid, 256, 0, stream>>>(hbuf, W_src2, node_perm, ntoff, x_src);
    scores_k<<<NN / 4, 256, 0, stream>>>(x_src, hbuf, att_src2, u2, ntype, s_src, s_dst);
    sedge_k<<<(NE + 255) / 256, 256, 0, stream>>>(eattr, etype, v2, sedge);
    aggregate_k<<<NN / 4, 256, 0, stream>>>(x_src, s_src, s_dst, sedge, row_ptr, perm,
                                            srca, etype, bias2, nullptr, nullptr,
                                            (float*)d_out, 2);
}

// Round 3
// 632.818 us; speedup vs baseline: 2.1058x; 1.2785x over previous
//
#include <hip/hip_runtime.h>

#define NN 50000
#define NE 400000
#define NH 4
#define NTY 3
#define ETY 4
#define EDIM 32
#define NBLK 196   // ceil(NN/256)
// Both layers: K = 256 input dim, 256 = HEADS*C output dim (C=64)

// ---------------------------------------------------------------- prep: fold
// u[tn][t][h][d] = sum_c W_dst[tn][d][h*64+c] * att_dst[t][h][c]   (12288 each)
// v[t][h][d]     = sum_c W_edge[t][d][h*64+c] * att_edge[t][h][c]  (512 each)
__global__ __launch_bounds__(256) void prep_fold(
    const float* __restrict__ W_dst1, const float* __restrict__ att_dst1,
    const float* __restrict__ W_edge1, const float* __restrict__ att_edge1,
    const float* __restrict__ W_dst2, const float* __restrict__ att_dst2,
    const float* __restrict__ W_edge2, const float* __restrict__ att_edge2,
    float* __restrict__ u1, float* __restrict__ u2,
    float* __restrict__ v1, float* __restrict__ v2)
{
    int idx = blockIdx.x * 256 + threadIdx.x;   // 25600 total
    if (idx < 24576) {
        const float* W; const float* A; float* U; int i;
        if (idx < 12288) { W = W_dst1; A = att_dst1; U = u1; i = idx; }
        else             { W = W_dst2; A = att_dst2; U = u2; i = idx - 12288; }
        int d = i & 255, h = (i >> 8) & 3, t = (i >> 10) & 3, tn = i >> 12;
        const float* wp = W + tn * 65536 + d * 256 + h * 64;
        const float* ap = A + t * 256 + h * 64;
        float s = 0.f;
        #pragma unroll 8
        for (int c = 0; c < 64; ++c) s += wp[c] * ap[c];
        U[(tn * 16 + t * 4 + h) * 256 + d] = s;
    } else {
        int i = idx - 24576;
        const float* W; const float* A; float* V;
        if (i < 512) { W = W_edge1; A = att_edge1; V = v1; }
        else         { W = W_edge2; A = att_edge2; V = v2; i -= 512; }
        int d = i & 31, h = (i >> 5) & 3, t = i >> 7;
        const float* wp = W + t * (EDIM * 256) + d * 256 + h * 64;
        const float* ap = A + t * 256 + h * 64;
        float s = 0.f;
        #pragma unroll 8
        for (int c = 0; c < 64; ++c) s += wp[c] * ap[c];
        V[(t * 4 + h) * 32 + d] = s;
    }
}

// ---------------------------------------------------------------- CSR build
// Per-edge histogram (50K distinct counters -> low contention).
__global__ void hist_k(const int* __restrict__ dst, int* __restrict__ cnt)
{
    int i = blockIdx.x * 256 + threadIdx.x;
    if (i < NE) atomicAdd(&cnt[dst[i]], 1);
}

// Phase A: per-block sums of edge counts + node-type counts (packed 3x10 bit).
__global__ __launch_bounds__(256) void csr_blocksum(
    const int* __restrict__ cnt, const int* __restrict__ ntype,
    int* __restrict__ blks)  // [4][NBLK]
{
    int tid = threadIdx.x, b = blockIdx.x;
    int j = b * 256 + tid;
    int c = (j < NN) ? cnt[j] : 0;
    int t = (j < NN) ? ntype[j] : 3;
    int p = (t < 3) ? (1 << (t * 10)) : 0;
    #pragma unroll
    for (int d = 1; d < 64; d <<= 1) { c += __shfl_xor(c, d); p += __shfl_xor(p, d); }
    __shared__ int ws[2][4];
    int lane = tid & 63, w = tid >> 6;
    if (lane == 0) { ws[0][w] = c; ws[1][w] = p; }
    __syncthreads();
    if (tid == 0) {
        int C = ws[0][0] + ws[0][1] + ws[0][2] + ws[0][3];
        int P = ws[1][0] + ws[1][1] + ws[1][2] + ws[1][3];
        blks[b]            = C;
        blks[NBLK + b]     = P & 1023;
        blks[2 * NBLK + b] = (P >> 10) & 1023;
        blks[3 * NBLK + b] = (P >> 20) & 1023;
    }
}

// Phase B: exclusive scan of the NBLK block sums (4 streams), totals -> ntoff.
__global__ __launch_bounds__(256) void csr_scanmid(int* __restrict__ blks,
                                                   int* __restrict__ ntoff)
{
    __shared__ int4 part[256];
    int tid = threadIdx.x;
    int4 v = make_int4(0, 0, 0, 0);
    if (tid < NBLK)
        v = make_int4(blks[tid], blks[NBLK + tid], blks[2 * NBLK + tid], blks[3 * NBLK + tid]);
    int4 orig = v;
    part[tid] = v;
    __syncthreads();
    for (int off = 1; off < 256; off <<= 1) {
        int4 u = (tid >= off) ? part[tid - off] : make_int4(0, 0, 0, 0);
        __syncthreads();
        part[tid].x += u.x; part[tid].y += u.y; part[tid].z += u.z; part[tid].w += u.w;
        __syncthreads();
    }
    int4 inc = part[tid];
    if (tid < NBLK) {
        blks[tid]            = inc.x - orig.x;
        blks[NBLK + tid]     = inc.y - orig.y;
        blks[2 * NBLK + tid] = inc.z - orig.z;
        blks[3 * NBLK + tid] = inc.w - orig.w;
    }
    if (tid == 255) {
        ntoff[0] = 0; ntoff[1] = inc.y; ntoff[2] = inc.y + inc.z;
        ntoff[3] = inc.y + inc.z + inc.w;
    }
}

// Phase C: block-local exclusive scan + block offsets -> row_ptr, node_perm.
__global__ __launch_bounds__(256) void csr_apply(
    const int* __restrict__ cnt, const int* __restrict__ ntype,
    const int* __restrict__ blks, const int* __restrict__ ntoff,
    int* __restrict__ row_ptr, int* __restrict__ node_perm)
{
    int tid = threadIdx.x, b = blockIdx.x;
    int j = b * 256 + tid;
    int c = (j < NN) ? cnt[j] : 0;
    int t = (j < NN) ? ntype[j] : 3;
    int p = (t < 3) ? (1 << (t * 10)) : 0;
    int lane = tid & 63, w = tid >> 6;
    int ic = c, ip = p;
    #pragma unroll
    for (int d = 1; d < 64; d <<= 1) {
        int uc = __shfl_up(ic, d), up = __shfl_up(ip, d);
        if (lane >= d) { ic += uc; ip += up; }
    }
    __shared__ int ws[2][4];
    if (lane == 63) { ws[0][w] = ic; ws[1][w] = ip; }
    __syncthreads();
    int coff = 0, poff = 0;
    for (int i = 0; i < w; ++i) { coff += ws[0][i]; poff += ws[1][i]; }
    int exc  = ic - c + coff;   // exclusive edge-count prefix within block
    int expp = ip - p + poff;   // exclusive packed type prefix within block
    if (j < NN) {
        row_ptr[j] = blks[b] + exc;
        if (t < 3) {
            int tb   = blks[(t + 1) * NBLK + b];
            int tpfx = (expp >> (t * 10)) & 1023;
            node_perm[ntoff[t] + tb + tpfx] = j;
        }
    }
    if (j == 0) row_ptr[NN] = NE;
}

__global__ void scatter_k(const int* __restrict__ dst,
                          const int* __restrict__ row_ptr, int* __restrict__ cursor,
                          int* __restrict__ perm)
{
    int i = blockIdx.x * 256 + threadIdx.x;
    if (i < NE) {
        int d = dst[i];
        int pos = row_ptr[d] + atomicAdd(&cursor[d], 1);
        perm[pos] = i;
    }
}

// ---------------------------------------------------------------- GEMM
// Row-gathered tiled SGEMM: rows bucketed by node type (blockIdx.z = type).
// xout[node_perm[r], :] = xin[node_perm[r], :] @ W[type]   (K=256, N=256)
#define TM 64
#define TN 64
#define TK 16
__global__ __launch_bounds__(256) void gemm_rows(
    const float* __restrict__ xin, const float* __restrict__ Wall,
    const int* __restrict__ node_perm, const int* __restrict__ ntoff,
    float* __restrict__ xout)
{
    int t = blockIdx.z;
    int seg0 = ntoff[t], seg1 = ntoff[t + 1];
    int row0 = seg0 + blockIdx.x * TM;
    if (row0 >= seg1) return;
    int col0 = blockIdx.y * TN;
    const float* W = Wall + (size_t)t * 256 * 256;

    __shared__ int rows[TM];
    __shared__ __align__(16) float At[TK][TM + 4];  // transposed A tile
    __shared__ __align__(16) float Bt[TK][TN];

    int tid = threadIdx.x;
    if (tid < TM) {
        int rp = row0 + tid;
        rows[tid] = (rp < seg1) ? node_perm[rp] : -1;
    }
    __syncthreads();

    int ty = tid >> 4, tx = tid & 15;      // micro-tile 4x4
    int lr = tid >> 2, lc4 = (tid & 3) * 4;       // A-load mapping
    int bk = tid >> 4, bc4 = (tid & 15) * 4;      // B-load mapping

    int grA = rows[lr];
    const float* arow = xin + (size_t)(grA < 0 ? 0 : grA) * 256;

    float acc[4][4] = {};

    for (int k0 = 0; k0 < 256; k0 += TK) {
        float4 av = make_float4(0.f, 0.f, 0.f, 0.f);
        if (grA >= 0) av = *(const float4*)(arow + k0 + lc4);
        At[lc4 + 0][lr] = av.x; At[lc4 + 1][lr] = av.y;
        At[lc4 + 2][lr] = av.z; At[lc4 + 3][lr] = av.w;
        float4 bv = *(const float4*)(W + (size_t)(k0 + bk) * 256 + col0 + bc4);
        *(float4*)&Bt[bk][bc4] = bv;
        __syncthreads();
        #pragma unroll
        for (int k = 0; k < TK; ++k) {
            float4 a = *(const float4*)&At[k][ty * 4];
            float4 b = *(const float4*)&Bt[k][tx * 4];
            acc[0][0] += a.x * b.x; acc[0][1] += a.x * b.y; acc[0][2] += a.x * b.z; acc[0][3] += a.x * b.w;
            acc[1][0] += a.y * b.x; acc[1][1] += a.y * b.y; acc[1][2] += a.y * b.z; acc[1][3] += a.y * b.w;
            acc[2][0] += a.z * b.x; acc[2][1] += a.z * b.y; acc[2][2] += a.z * b.z; acc[2][3] += a.z * b.w;
            acc[3][0] += a.w * b.x; acc[3][1] += a.w * b.y; acc[3][2] += a.w * b.z; acc[3][3] += a.w * b.w;
        }
        __syncthreads();
    }
    #pragma unroll
    for (int i = 0; i < 4; ++i) {
        int gr = rows[ty * 4 + i];
        if (gr >= 0) {
            float4 o = make_float4(acc[i][0], acc[i][1], acc[i][2], acc[i][3]);
            *(float4*)(xout + (size_t)gr * 256 + col0 + tx * 4) = o;
        }
    }
}

// ---------------------------------------------------------------- scores
// s_src[n,t,h] = sum_c x_src[n,h,c]*att_src[t,h,c]
// s_dst[n,t,h] = sum_d xin[n,d]*u[tn,t,h,d]
__global__ __launch_bounds__(256) void scores_k(
    const float* __restrict__ x_src, const float* __restrict__ xin,
    const float* __restrict__ att_src, const float* __restrict__ u,
    const int* __restrict__ ntype,
    float* __restrict__ s_src, float* __restrict__ s_dst)
{
    int n = blockIdx.x * 4 + (threadIdx.x >> 6);
    int lane = threadIdx.x & 63;
    float4 xs = *(const float4*)(x_src + (size_t)n * 256 + lane * 4);
    float4 xi = *(const float4*)(xin + (size_t)n * 256 + lane * 4);
    int tn = ntype[n];
    int h = lane >> 4;
    #pragma unroll
    for (int t = 0; t < 4; ++t) {
        float4 a = *(const float4*)(att_src + t * 256 + lane * 4);
        float p = xs.x * a.x + xs.y * a.y + xs.z * a.z + xs.w * a.w;
        p += __shfl_xor(p, 1); p += __shfl_xor(p, 2);
        p += __shfl_xor(p, 4); p += __shfl_xor(p, 8);
        if ((lane & 15) == 0) s_src[(size_t)n * 16 + t * 4 + h] = p;
    }
    #pragma unroll
    for (int th = 0; th < 16; ++th) {
        float4 uu = *(const float4*)(u + (size_t)(tn * 16 + th) * 256 + lane * 4);
        float p = xi.x * uu.x + xi.y * uu.y + xi.z * uu.z + xi.w * uu.w;
        p += __shfl_xor(p, 1); p += __shfl_xor(p, 2); p += __shfl_xor(p, 4);
        p += __shfl_xor(p, 8); p += __shfl_xor(p, 16); p += __shfl_xor(p, 32);
        if (lane == 0) s_dst[(size_t)n * 16 + th] = p;
    }
}

// ---------------------------------------------------------------- edge scores
__global__ void sedge_k(const float* __restrict__ eattr, const int* __restrict__ etype,
                        const float* __restrict__ v, float* __restrict__ sedge)
{
    int e = blockIdx.x * 256 + threadIdx.x;
    if (e >= NE) return;
    int t = etype[e];
    float4 ea[8];
    #pragma unroll
    for (int i = 0; i < 8; ++i) ea[i] = *(const float4*)(eattr + (size_t)e * 32 + i * 4);
    #pragma unroll
    for (int h = 0; h < 4; ++h) {
        const float* vp = v + (t * 4 + h) * 32;
        float s = 0.f;
        #pragma unroll
        for (int i = 0; i < 8; ++i) {
            float4 vv = *(const float4*)(vp + i * 4);
            s += ea[i].x * vv.x + ea[i].y * vv.y + ea[i].z * vv.z + ea[i].w * vv.w;
        }
        sedge[(size_t)e * 4 + h] = s;
    }
}

// ---------------------------------------------------------------- aggregate
// One wave per dst node: single-pass online softmax over its CSR edges,
// gathering x_src[src] rows. Fused epilogue:
//   mode 1: +bias, LayerNorm, ELU  -> h (N,256)
//   mode 2: mean over heads +bias  -> out (N,64)
__global__ __launch_bounds__(256) void aggregate_k(
    const float* __restrict__ x_src, const float* __restrict__ s_src,
    const float* __restrict__ s_dst, const float* __restrict__ sedge,
    const int* __restrict__ row_ptr, const int* __restrict__ perm,
    const int* __restrict__ srca, const int* __restrict__ etype,
    const float* __restrict__ bias, const float* __restrict__ gamma,
    const float* __restrict__ beta, float* __restrict__ out, int mode)
{
    int n = blockIdx.x * 4 + (threadIdx.x >> 6);
    int lane = threadIdx.x & 63;
    int h2 = lane >> 4;                    // head owned by this lane's channels
    int beg = row_ptr[n], end = row_ptr[n + 1];

    float sd0 = s_dst[(size_t)n * 16 + 0 * 4 + h2];
    float sd1 = s_dst[(size_t)n * 16 + 1 * 4 + h2];
    float sd2 = s_dst[(size_t)n * 16 + 2 * 4 + h2];
    float sd3 = s_dst[(size_t)n * 16 + 3 * 4 + h2];

    float m = -1e30f, den = 0.f;
    float4 acc = make_float4(0.f, 0.f, 0.f, 0.f);
    for (int i = beg; i < end; ++i) {
        int e = perm[i];
        int s = srca[e];
        int t = etype[e];
        float sdv = (t == 0) ? sd0 : (t == 1) ? sd1 : (t == 2) ? sd2 : sd3;
        float a = s_src[(size_t)s * 16 + t * 4 + h2] + sdv + sedge[(size_t)e * 4 + h2];
        a = (a >= 0.f) ? a : 0.2f * a;     // LeakyReLU
        float mn = fmaxf(m, a);
        float sc = __expf(m - mn);         // first iter: exp(-1e30) = 0
        float ae = __expf(a - mn);
        den = den * sc + ae;
        float4 xv = *(const float4*)(x_src + (size_t)s * 256 + lane * 4);
        acc.x = acc.x * sc + xv.x * ae;
        acc.y = acc.y * sc + xv.y * ae;
        acc.z = acc.z * sc + xv.z * ae;
        acc.w = acc.w * sc + xv.w * ae;
        m = mn;
    }
    float inv = 1.f / (den + 1e-16f);
    acc.x *= inv; acc.y *= inv; acc.z *= inv; acc.w *= inv;

    if (mode == 1) {
        float4 bb = *(const float4*)(bias + lane * 4);
        float vals[4] = { acc.x + bb.x, acc.y + bb.y, acc.z + bb.z, acc.w + bb.w };
        float s = vals[0] + vals[1] + vals[2] + vals[3];
        s += __shfl_xor(s, 1); s += __shfl_xor(s, 2); s += __shfl_xor(s, 4);
        s += __shfl_xor(s, 8); s += __shfl_xor(s, 16); s += __shfl_xor(s, 32);
        float mu = s * (1.f / 256.f);
        float q = 0.f;
        #pragma unroll
        for (int j = 0; j < 4; ++j) { float d = vals[j] - mu; q += d * d; }
        q += __shfl_xor(q, 1); q += __shfl_xor(q, 2); q += __shfl_xor(q, 4);
        q += __shfl_xor(q, 8); q += __shfl_xor(q, 16); q += __shfl_xor(q, 32);
        float r = rsqrtf(q * (1.f / 256.f) + 1e-5f);
        float4 gg = *(const float4*)(gamma + lane * 4);
        float4 be = *(const float4*)(beta + lane * 4);
        float4 o;
        float y;
        y = (vals[0] - mu) * r * gg.x + be.x; o.x = (y > 0.f) ? y : (__expf(y) - 1.f);
        y = (vals[1] - mu) * r * gg.y + be.y; o.y = (y > 0.f) ? y : (__expf(y) - 1.f);
        y = (vals[2] - mu) * r * gg.z + be.z; o.z = (y > 0.f) ? y : (__expf(y) - 1.f);
        y = (vals[3] - mu) * r * gg.w + be.w; o.w = (y > 0.f) ? y : (__expf(y) - 1.f);
        *(float4*)(out + (size_t)n * 256 + lane * 4) = o;
    } else {
        acc.x += __shfl_xor(acc.x, 16); acc.x += __shfl_xor(acc.x, 32);
        acc.y += __shfl_xor(acc.y, 16); acc.y += __shfl_xor(acc.y, 32);
        acc.z += __shfl_xor(acc.z, 16); acc.z += __shfl_xor(acc.z, 32);
        acc.w += __shfl_xor(acc.w, 16); acc.w += __shfl_xor(acc.w, 32);
        if (lane < 16) {
            float4 bb = *(const float4*)(bias + lane * 4);
            float4 o;
            o.x = acc.x * 0.25f + bb.x;
            o.y = acc.y * 0.25f + bb.y;
            o.z = acc.z * 0.25f + bb.z;
            o.w = acc.w * 0.25f + bb.w;
            *(float4*)(out + (size_t)n * 64 + lane * 4) = o;
        }
    }
}

// ---------------------------------------------------------------- launch
extern "C" void kernel_launch(void* const* d_in, const int* in_sizes, int n_in,
                              void* d_out, int out_size, void* d_ws, size_t ws_size,
                              hipStream_t stream)
{
    (void)in_sizes; (void)n_in; (void)out_size;
    const float* x        = (const float*)d_in[0];
    const int*   ei       = (const int*)d_in[1];
    const int*   ntype    = (const int*)d_in[2];
    const int*   etype    = (const int*)d_in[3];
    const float* eattr    = (const float*)d_in[4];
    const float* W_src1   = (const float*)d_in[5];
    const float* W_dst1   = (const float*)d_in[6];
    const float* att_src1 = (const float*)d_in[7];
    const float* att_dst1 = (const float*)d_in[8];
    const float* W_edge1  = (const float*)d_in[9];
    const float* att_edge1= (const float*)d_in[10];
    const float* bias1    = (const float*)d_in[11];
    const float* gamma1   = (const float*)d_in[12];
    const float* beta1    = (const float*)d_in[13];
    const float* W_src2   = (const float*)d_in[14];
    const float* W_dst2   = (const float*)d_in[15];
    const float* att_src2 = (const float*)d_in[16];
    const float* att_dst2 = (const float*)d_in[17];
    const float* W_edge2  = (const float*)d_in[18];
    const float* att_edge2= (const float*)d_in[19];
    const float* bias2    = (const float*)d_in[20];

    char* w = (char*)d_ws;
    size_t off = 0;
    auto carve = [&](size_t bytes) -> char* {
        char* p = w + off;
        off = (off + bytes + 255) & ~(size_t)255;
        return p;
    };
    float* x_src    = (float*)carve((size_t)NN * 256 * 4);
    float* hbuf     = (float*)carve((size_t)NN * 256 * 4);
    float* s_src    = (float*)carve((size_t)NN * 16 * 4);
    float* s_dst    = (float*)carve((size_t)NN * 16 * 4);
    float* sedge    = (float*)carve((size_t)NE * 4 * 4);
    int*   cnt      = (int*)carve((size_t)(2 * NN) * 4);
    int*   cursor   = cnt + NN;
    int*   row_ptr  = (int*)carve((size_t)(NN + 1) * 4);
    int*   perm     = (int*)carve((size_t)NE * 4);
    int*   node_perm= (int*)carve((size_t)NN * 4);
    int*   ntoff    = (int*)carve(4 * 4);
    int*   blks     = (int*)carve((size_t)(4 * NBLK) * 4);
    float* u1       = (float*)carve(12288 * 4);
    float* u2       = (float*)carve(12288 * 4);
    float* v1       = (float*)carve(512 * 4);
    float* v2       = (float*)carve(512 * 4);
    if (off > ws_size) return;  // workspace too small; bail without corrupting

    const int* srca = ei;
    const int* dsta = ei + NE;

    hipMemsetAsync(cnt, 0, (size_t)(2 * NN) * 4, stream);

    prep_fold<<<100, 256, 0, stream>>>(W_dst1, att_dst1, W_edge1, att_edge1,
                                       W_dst2, att_dst2, W_edge2, att_edge2,
                                       u1, u2, v1, v2);
    hist_k<<<(NE + 255) / 256, 256, 0, stream>>>(dsta, cnt);
    csr_blocksum<<<NBLK, 256, 0, stream>>>(cnt, ntype, blks);
    csr_scanmid<<<1, 256, 0, stream>>>(blks, ntoff);
    csr_apply<<<NBLK, 256, 0, stream>>>(cnt, ntype, blks, ntoff, row_ptr, node_perm);
    scatter_k<<<(NE + 255) / 256, 256, 0, stream>>>(dsta, row_ptr, cursor, perm);

    dim3 ggrid((NN + TM - 1) / TM, 256 / TN, NTY);

    // ---- layer 1
    gemm_rows<<<ggrid, 256, 0, stream>>>(x, W_src1, node_perm, ntoff, x_src);
    scores_k<<<NN / 4, 256, 0, stream>>>(x_src, x, att_src1, u1, ntype, s_src, s_dst);
    sedge_k<<<(NE + 255) / 256, 256, 0, stream>>>(eattr, etype, v1, sedge);
    aggregate_k<<<NN / 4, 256, 0, stream>>>(x_src, s_src, s_dst, sedge, row_ptr, perm,
                                            srca, etype, bias1, gamma1, beta1, hbuf, 1);

    // ---- layer 2
    gemm_rows<<<ggrid, 256, 0, stream>>>(hbuf, W_src2, node_perm, ntoff, x_src);
    scores_k<<<NN / 4, 256, 0, stream>>>(x_src, hbuf, att_src2, u2, ntype, s_src, s_dst);
    sedge_k<<<(NE + 255) / 256, 256, 0, stream>>>(eattr, etype, v2, sedge);
    aggregate_k<<<NN / 4, 256, 0, stream>>>(x_src, s_src, s_dst, sedge, row_ptr, perm,
                                            srca, etype, bias2, nullptr, nullptr,
                                            (float*)d_out, 2);
}

// Round 4
// 544.147 us; speedup vs baseline: 2.4489x; 1.1630x over previous
//
#include <hip/hip_runtime.h>

#define NN 50000
#define NE 400000
#define NH 4
#define NTY 3
#define ETY 4
#define EDIM 32
#define NBLK 196   // ceil(NN/256)

typedef __attribute__((ext_vector_type(8))) short bf16x8;
typedef __attribute__((ext_vector_type(4))) float f32x4;

static __device__ __forceinline__ unsigned short f2bf(float f) {
    unsigned u = __float_as_uint(f);
    unsigned r = (u + 0x7FFFu + ((u >> 16) & 1u)) >> 16;   // RNE
    return (unsigned short)r;
}
static __device__ __forceinline__ float bf2f(unsigned short s) {
    return __uint_as_float(((unsigned)s) << 16);
}

// ---------------------------------------------------------------- convert x -> bf16
__global__ __launch_bounds__(256) void convert_k(const float* __restrict__ x,
                                                 ushort* __restrict__ xb)
{
    int i = blockIdx.x * 256 + threadIdx.x;          // one float4 per thread
    if (i >= NN * 64) return;
    float4 v = ((const float4*)x)[i];
    ushort4 o;
    o.x = f2bf(v.x); o.y = f2bf(v.y); o.z = f2bf(v.z); o.w = f2bf(v.w);
    ((ushort4*)xb)[i] = o;
}

// ---------------------------------------------------------------- prep: fold u,v
__global__ __launch_bounds__(256) void prep_fold(
    const float* __restrict__ W_dst1, const float* __restrict__ att_dst1,
    const float* __restrict__ W_edge1, const float* __restrict__ att_edge1,
    const float* __restrict__ W_dst2, const float* __restrict__ att_dst2,
    const float* __restrict__ W_edge2, const float* __restrict__ att_edge2,
    float* __restrict__ u1, float* __restrict__ u2,
    float* __restrict__ v1, float* __restrict__ v2)
{
    int idx = blockIdx.x * 256 + threadIdx.x;   // 25600 total
    if (idx < 24576) {
        const float* W; const float* A; float* U; int i;
        if (idx < 12288) { W = W_dst1; A = att_dst1; U = u1; i = idx; }
        else             { W = W_dst2; A = att_dst2; U = u2; i = idx - 12288; }
        int d = i & 255, h = (i >> 8) & 3, t = (i >> 10) & 3, tn = i >> 12;
        const float* wp = W + tn * 65536 + d * 256 + h * 64;
        const float* ap = A + t * 256 + h * 64;
        float s = 0.f;
        #pragma unroll 8
        for (int c = 0; c < 64; ++c) s += wp[c] * ap[c];
        U[(tn * 16 + t * 4 + h) * 256 + d] = s;
    } else {
        int i = idx - 24576;
        const float* W; const float* A; float* V;
        if (i < 512) { W = W_edge1; A = att_edge1; V = v1; }
        else         { W = W_edge2; A = att_edge2; V = v2; i -= 512; }
        int d = i & 31, h = (i >> 5) & 3, t = i >> 7;
        const float* wp = W + t * (EDIM * 256) + d * 256 + h * 64;
        const float* ap = A + t * 256 + h * 64;
        float s = 0.f;
        #pragma unroll 8
        for (int c = 0; c < 64; ++c) s += wp[c] * ap[c];
        V[(t * 4 + h) * 32 + d] = s;
    }
}

// ---------------------------------------------------------------- prep: Wt bf16
// Wt[t][n][k] = bf16(W_src[t][k][n])  for both layers (coalesced reads over n).
__global__ __launch_bounds__(256) void prep_wt(
    const float* __restrict__ W1, const float* __restrict__ W2,
    ushort* __restrict__ Wt1, ushort* __restrict__ Wt2)
{
    int idx = blockIdx.x * 256 + threadIdx.x;   // 393216 total
    const int HALF = 196608;
    const float* W = (idx < HALF) ? W1 : W2;
    ushort* O = (idx < HALF) ? Wt1 : Wt2;
    int i = (idx < HALF) ? idx : idx - HALF;
    int n = i & 255, k = (i >> 8) & 255, t = i >> 16;
    O[t * 65536 + n * 256 + k] = f2bf(W[t * 65536 + k * 256 + n]);
}

// ---------------------------------------------------------------- CSR build
__global__ void hist_k(const int* __restrict__ dst, int* __restrict__ cnt)
{
    int i = blockIdx.x * 256 + threadIdx.x;
    if (i < NE) atomicAdd(&cnt[dst[i]], 1);
}

__global__ __launch_bounds__(256) void csr_blocksum(
    const int* __restrict__ cnt, const int* __restrict__ ntype,
    int* __restrict__ blks)  // [4][NBLK]
{
    int tid = threadIdx.x, b = blockIdx.x;
    int j = b * 256 + tid;
    int c = (j < NN) ? cnt[j] : 0;
    int t = (j < NN) ? ntype[j] : 3;
    int p = (t < 3) ? (1 << (t * 10)) : 0;
    #pragma unroll
    for (int d = 1; d < 64; d <<= 1) { c += __shfl_xor(c, d); p += __shfl_xor(p, d); }
    __shared__ int ws[2][4];
    int lane = tid & 63, w = tid >> 6;
    if (lane == 0) { ws[0][w] = c; ws[1][w] = p; }
    __syncthreads();
    if (tid == 0) {
        int C = ws[0][0] + ws[0][1] + ws[0][2] + ws[0][3];
        int P = ws[1][0] + ws[1][1] + ws[1][2] + ws[1][3];
        blks[b]            = C;
        blks[NBLK + b]     = P & 1023;
        blks[2 * NBLK + b] = (P >> 10) & 1023;
        blks[3 * NBLK + b] = (P >> 20) & 1023;
    }
}

__global__ __launch_bounds__(256) void csr_scanmid(int* __restrict__ blks,
                                                   int* __restrict__ ntoff)
{
    __shared__ int4 part[256];
    int tid = threadIdx.x;
    int4 v = make_int4(0, 0, 0, 0);
    if (tid < NBLK)
        v = make_int4(blks[tid], blks[NBLK + tid], blks[2 * NBLK + tid], blks[3 * NBLK + tid]);
    int4 orig = v;
    part[tid] = v;
    __syncthreads();
    for (int off = 1; off < 256; off <<= 1) {
        int4 u = (tid >= off) ? part[tid - off] : make_int4(0, 0, 0, 0);
        __syncthreads();
        part[tid].x += u.x; part[tid].y += u.y; part[tid].z += u.z; part[tid].w += u.w;
        __syncthreads();
    }
    int4 inc = part[tid];
    if (tid < NBLK) {
        blks[tid]            = inc.x - orig.x;
        blks[NBLK + tid]     = inc.y - orig.y;
        blks[2 * NBLK + tid] = inc.z - orig.z;
        blks[3 * NBLK + tid] = inc.w - orig.w;
    }
    if (tid == 255) {
        ntoff[0] = 0; ntoff[1] = inc.y; ntoff[2] = inc.y + inc.z;
        ntoff[3] = inc.y + inc.z + inc.w;
    }
}

__global__ __launch_bounds__(256) void csr_apply(
    const int* __restrict__ cnt, const int* __restrict__ ntype,
    const int* __restrict__ blks, const int* __restrict__ ntoff,
    int* __restrict__ row_ptr, int* __restrict__ node_perm)
{
    int tid = threadIdx.x, b = blockIdx.x;
    int j = b * 256 + tid;
    int c = (j < NN) ? cnt[j] : 0;
    int t = (j < NN) ? ntype[j] : 3;
    int p = (t < 3) ? (1 << (t * 10)) : 0;
    int lane = tid & 63, w = tid >> 6;
    int ic = c, ip = p;
    #pragma unroll
    for (int d = 1; d < 64; d <<= 1) {
        int uc = __shfl_up(ic, d), up = __shfl_up(ip, d);
        if (lane >= d) { ic += uc; ip += up; }
    }
    __shared__ int ws[2][4];
    if (lane == 63) { ws[0][w] = ic; ws[1][w] = ip; }
    __syncthreads();
    int coff = 0, poff = 0;
    for (int i = 0; i < w; ++i) { coff += ws[0][i]; poff += ws[1][i]; }
    int exc  = ic - c + coff;
    int expp = ip - p + poff;
    if (j < NN) {
        row_ptr[j] = blks[b] + exc;
        if (t < 3) {
            int tb   = blks[(t + 1) * NBLK + b];
            int tpfx = (expp >> (t * 10)) & 1023;
            node_perm[ntoff[t] + tb + tpfx] = j;
        }
    }
    if (j == 0) row_ptr[NN] = NE;
}

__global__ void scatter_k(const int* __restrict__ dst,
                          const int* __restrict__ row_ptr, int* __restrict__ cursor,
                          int* __restrict__ perm)
{
    int i = blockIdx.x * 256 + threadIdx.x;
    if (i < NE) {
        int d = dst[i];
        int pos = row_ptr[d] + atomicAdd(&cursor[d], 1);
        perm[pos] = i;
    }
}

// ---------------------------------------------------------------- bf16 MFMA GEMM
// Block: 64 gathered rows x 64 out-channels, full K=256 in LDS (single shot).
// A-operand = Wt[n][k] (pre-transposed bf16), B-operand = X rows (bf16).
// D[m=n-ch][col=x-row]; LDS XOR-swizzled by ((row&7)<<4) for conflict-free b128.
#define GROWS 64
#define GNCH 64
__global__ __launch_bounds__(256) void gemm_bf16(
    const ushort* __restrict__ xb, const ushort* __restrict__ Wtb,
    const int* __restrict__ node_perm, const int* __restrict__ ntoff,
    ushort* __restrict__ xout)
{
    int t = blockIdx.z;
    int seg0 = ntoff[t], seg1 = ntoff[t + 1];
    int row0 = seg0 + blockIdx.x * GROWS;
    if (row0 >= seg1) return;
    int nb = blockIdx.y * GNCH;

    __shared__ __align__(16) ushort Xl[GROWS * 256];  // 32 KB
    __shared__ __align__(16) ushort Wl[GNCH * 256];   // 32 KB

    int tid = threadIdx.x;
    int w = tid >> 6, l = tid & 63;
    int lhalf = l >> 5;
    int kb = (l & 31) * 16;                 // byte offset within a 512B row
    const ushort* wsrc = Wtb + (size_t)t * 65536;

    #pragma unroll
    for (int it = 0; it < 8; ++it) {
        int row = w * 16 + it * 2 + lhalf;  // 0..63
        int rp = row0 + row;
        int gr = (rp < seg1) ? node_perm[rp] : 0;
        uint4 xv = *(const uint4*)((const char*)(xb + (size_t)gr * 256) + kb);
        *(uint4*)((char*)Xl + row * 512 + (kb ^ ((row & 7) << 4))) = xv;
        uint4 wv = *(const uint4*)((const char*)(wsrc + (size_t)(nb + row) * 256) + kb);
        *(uint4*)((char*)Wl + row * 512 + (kb ^ ((row & 7) << 4))) = wv;
    }
    __syncthreads();

    int g = l >> 4;          // k-group 0..3
    int r16 = l & 15;

    f32x4 acc0 = {0.f, 0.f, 0.f, 0.f}, acc1 = acc0, acc2 = acc0, acc3 = acc0;
    int wrow = w * 16 + r16;
    const char* wbase = (const char*)Wl + wrow * 512;
    int wsw = (wrow & 7) << 4;

    #pragma unroll
    for (int ks = 0; ks < 8; ++ks) {
        int kbyte = ks * 64 + g * 16;
        bf16x8 a = *(const bf16x8*)(wbase + (kbyte ^ wsw));
        bf16x8 b0 = *(const bf16x8*)((const char*)Xl + (0 * 16 + r16) * 512 + (kbyte ^ ((r16 & 7) << 4)));
        bf16x8 b1 = *(const bf16x8*)((const char*)Xl + (16 + r16) * 512 + (kbyte ^ (((16 + r16) & 7) << 4)));
        bf16x8 b2 = *(const bf16x8*)((const char*)Xl + (32 + r16) * 512 + (kbyte ^ (((32 + r16) & 7) << 4)));
        bf16x8 b3 = *(const bf16x8*)((const char*)Xl + (48 + r16) * 512 + (kbyte ^ (((48 + r16) & 7) << 4)));
        acc0 = __builtin_amdgcn_mfma_f32_16x16x32_bf16(a, b0, acc0, 0, 0, 0);
        acc1 = __builtin_amdgcn_mfma_f32_16x16x32_bf16(a, b1, acc1, 0, 0, 0);
        acc2 = __builtin_amdgcn_mfma_f32_16x16x32_bf16(a, b2, acc2, 0, 0, 0);
        acc3 = __builtin_amdgcn_mfma_f32_16x16x32_bf16(a, b3, acc3, 0, 0, 0);
    }

    int n = nb + w * 16 + g * 4;            // 4 consecutive channels per lane
    f32x4 aa[4] = {acc0, acc1, acc2, acc3};
    #pragma unroll
    for (int fr = 0; fr < 4; ++fr) {
        int rp = row0 + fr * 16 + r16;
        if (rp < seg1) {
            int gr = node_perm[rp];
            ushort4 o;
            o.x = f2bf(aa[fr][0]); o.y = f2bf(aa[fr][1]);
            o.z = f2bf(aa[fr][2]); o.w = f2bf(aa[fr][3]);
            *(ushort4*)(xout + (size_t)gr * 256 + n) = o;
        }
    }
}

// ---------------------------------------------------------------- scores
__global__ __launch_bounds__(256) void scores_k(
    const ushort* __restrict__ xsb, const ushort* __restrict__ xib,
    const float* __restrict__ att_src, const float* __restrict__ u,
    const int* __restrict__ ntype,
    float* __restrict__ s_src, float* __restrict__ s_dst)
{
    int n = blockIdx.x * 4 + (threadIdx.x >> 6);
    int lane = threadIdx.x & 63;
    ushort4 q4 = *(const ushort4*)(xsb + (size_t)n * 256 + lane * 4);
    ushort4 i4 = *(const ushort4*)(xib + (size_t)n * 256 + lane * 4);
    float xs0 = bf2f(q4.x), xs1 = bf2f(q4.y), xs2 = bf2f(q4.z), xs3 = bf2f(q4.w);
    float xi0 = bf2f(i4.x), xi1 = bf2f(i4.y), xi2 = bf2f(i4.z), xi3 = bf2f(i4.w);
    int tn = ntype[n];
    int h = lane >> 4;
    #pragma unroll
    for (int t = 0; t < 4; ++t) {
        float4 a = *(const float4*)(att_src + t * 256 + lane * 4);
        float p = xs0 * a.x + xs1 * a.y + xs2 * a.z + xs3 * a.w;
        p += __shfl_xor(p, 1); p += __shfl_xor(p, 2);
        p += __shfl_xor(p, 4); p += __shfl_xor(p, 8);
        if ((lane & 15) == 0) s_src[(size_t)n * 16 + t * 4 + h] = p;
    }
    #pragma unroll
    for (int th = 0; th < 16; ++th) {
        float4 uu = *(const float4*)(u + (size_t)(tn * 16 + th) * 256 + lane * 4);
        float p = xi0 * uu.x + xi1 * uu.y + xi2 * uu.z + xi3 * uu.w;
        p += __shfl_xor(p, 1); p += __shfl_xor(p, 2); p += __shfl_xor(p, 4);
        p += __shfl_xor(p, 8); p += __shfl_xor(p, 16); p += __shfl_xor(p, 32);
        if (lane == 0) s_dst[(size_t)n * 16 + th] = p;
    }
}

// ---------------------------------------------------------------- edge scores
__global__ void sedge_k(const float* __restrict__ eattr, const int* __restrict__ etype,
                        const float* __restrict__ v, float* __restrict__ sedge)
{
    int e = blockIdx.x * 256 + threadIdx.x;
    if (e >= NE) return;
    int t = etype[e];
    float4 ea[8];
    #pragma unroll
    for (int i = 0; i < 8; ++i) ea[i] = *(const float4*)(eattr + (size_t)e * 32 + i * 4);
    #pragma unroll
    for (int h = 0; h < 4; ++h) {
        const float* vp = v + (t * 4 + h) * 32;
        float s = 0.f;
        #pragma unroll
        for (int i = 0; i < 8; ++i) {
            float4 vv = *(const float4*)(vp + i * 4);
            s += ea[i].x * vv.x + ea[i].y * vv.y + ea[i].z * vv.z + ea[i].w * vv.w;
        }
        sedge[(size_t)e * 4 + h] = s;
    }
}

// ---------------------------------------------------------------- aggregate
// One wave per dst node: online softmax over CSR edges, bf16 message gather.
//   mode 1: +bias, LayerNorm, ELU  -> bf16 h (N,256)
//   mode 2: mean over heads +bias  -> f32 out (N,64)
__global__ __launch_bounds__(256) void aggregate_k(
    const ushort* __restrict__ xsb, const float* __restrict__ s_src,
    const float* __restrict__ s_dst, const float* __restrict__ sedge,
    const int* __restrict__ row_ptr, const int* __restrict__ perm,
    const int* __restrict__ srca, const int* __restrict__ etype,
    const float* __restrict__ bias, const float* __restrict__ gamma,
    const float* __restrict__ beta, void* __restrict__ out, int mode)
{
    int n = blockIdx.x * 4 + (threadIdx.x >> 6);
    int lane = threadIdx.x & 63;
    int h2 = lane >> 4;
    int beg = row_ptr[n], end = row_ptr[n + 1];

    float sd0 = s_dst[(size_t)n * 16 + 0 * 4 + h2];
    float sd1 = s_dst[(size_t)n * 16 + 1 * 4 + h2];
    float sd2 = s_dst[(size_t)n * 16 + 2 * 4 + h2];
    float sd3 = s_dst[(size_t)n * 16 + 3 * 4 + h2];

    float m = -1e30f, den = 0.f;
    float4 acc = make_float4(0.f, 0.f, 0.f, 0.f);
    for (int i = beg; i < end; ++i) {
        int e = perm[i];
        int s = srca[e];
        int t = etype[e];
        float sdv = (t == 0) ? sd0 : (t == 1) ? sd1 : (t == 2) ? sd2 : sd3;
        float a = s_src[(size_t)s * 16 + t * 4 + h2] + sdv + sedge[(size_t)e * 4 + h2];
        a = (a >= 0.f) ? a : 0.2f * a;     // LeakyReLU
        float mn = fmaxf(m, a);
        float sc = __expf(m - mn);
        float ae = __expf(a - mn);
        den = den * sc + ae;
        ushort4 xv = *(const ushort4*)(xsb + (size_t)s * 256 + lane * 4);
        acc.x = acc.x * sc + bf2f(xv.x) * ae;
        acc.y = acc.y * sc + bf2f(xv.y) * ae;
        acc.z = acc.z * sc + bf2f(xv.z) * ae;
        acc.w = acc.w * sc + bf2f(xv.w) * ae;
        m = mn;
    }
    float inv = 1.f / (den + 1e-16f);
    acc.x *= inv; acc.y *= inv; acc.z *= inv; acc.w *= inv;

    if (mode == 1) {
        float4 bb = *(const float4*)(bias + lane * 4);
        float vals[4] = { acc.x + bb.x, acc.y + bb.y, acc.z + bb.z, acc.w + bb.w };
        float s = vals[0] + vals[1] + vals[2] + vals[3];
        s += __shfl_xor(s, 1); s += __shfl_xor(s, 2); s += __shfl_xor(s, 4);
        s += __shfl_xor(s, 8); s += __shfl_xor(s, 16); s += __shfl_xor(s, 32);
        float mu = s * (1.f / 256.f);
        float q = 0.f;
        #pragma unroll
        for (int j = 0; j < 4; ++j) { float d = vals[j] - mu; q += d * d; }
        q += __shfl_xor(q, 1); q += __shfl_xor(q, 2); q += __shfl_xor(q, 4);
        q += __shfl_xor(q, 8); q += __shfl_xor(q, 16); q += __shfl_xor(q, 32);
        float r = rsqrtf(q * (1.f / 256.f) + 1e-5f);
        float4 gg = *(const float4*)(gamma + lane * 4);
        float4 be = *(const float4*)(beta + lane * 4);
        ushort4 o; float y;
        y = (vals[0] - mu) * r * gg.x + be.x; o.x = f2bf((y > 0.f) ? y : (__expf(y) - 1.f));
        y = (vals[1] - mu) * r * gg.y + be.y; o.y = f2bf((y > 0.f) ? y : (__expf(y) - 1.f));
        y = (vals[2] - mu) * r * gg.z + be.z; o.z = f2bf((y > 0.f) ? y : (__expf(y) - 1.f));
        y = (vals[3] - mu) * r * gg.w + be.w; o.w = f2bf((y > 0.f) ? y : (__expf(y) - 1.f));
        *(ushort4*)((ushort*)out + (size_t)n * 256 + lane * 4) = o;
    } else {
        acc.x += __shfl_xor(acc.x, 16); acc.x += __shfl_xor(acc.x, 32);
        acc.y += __shfl_xor(acc.y, 16); acc.y += __shfl_xor(acc.y, 32);
        acc.z += __shfl_xor(acc.z, 16); acc.z += __shfl_xor(acc.z, 32);
        acc.w += __shfl_xor(acc.w, 16); acc.w += __shfl_xor(acc.w, 32);
        if (lane < 16) {
            float4 bb = *(const float4*)(bias + lane * 4);
            float4 o;
            o.x = acc.x * 0.25f + bb.x;
            o.y = acc.y * 0.25f + bb.y;
            o.z = acc.z * 0.25f + bb.z;
            o.w = acc.w * 0.25f + bb.w;
            *(float4*)((float*)out + (size_t)n * 64 + lane * 4) = o;
        }
    }
}

// ---------------------------------------------------------------- launch
extern "C" void kernel_launch(void* const* d_in, const int* in_sizes, int n_in,
                              void* d_out, int out_size, void* d_ws, size_t ws_size,
                              hipStream_t stream)
{
    (void)in_sizes; (void)n_in; (void)out_size;
    const float* x        = (const float*)d_in[0];
    const int*   ei       = (const int*)d_in[1];
    const int*   ntype    = (const int*)d_in[2];
    const int*   etype    = (const int*)d_in[3];
    const float* eattr    = (const float*)d_in[4];
    const float* W_src1   = (const float*)d_in[5];
    const float* W_dst1   = (const float*)d_in[6];
    const float* att_src1 = (const float*)d_in[7];
    const float* att_dst1 = (const float*)d_in[8];
    const float* W_edge1  = (const float*)d_in[9];
    const float* att_edge1= (const float*)d_in[10];
    const float* bias1    = (const float*)d_in[11];
    const float* gamma1   = (const float*)d_in[12];
    const float* beta1    = (const float*)d_in[13];
    const float* W_src2   = (const float*)d_in[14];
    const float* W_dst2   = (const float*)d_in[15];
    const float* att_src2 = (const float*)d_in[16];
    const float* att_dst2 = (const float*)d_in[17];
    const float* W_edge2  = (const float*)d_in[18];
    const float* att_edge2= (const float*)d_in[19];
    const float* bias2    = (const float*)d_in[20];

    char* w = (char*)d_ws;
    size_t off = 0;
    auto carve = [&](size_t bytes) -> char* {
        char* p = w + off;
        off = (off + bytes + 255) & ~(size_t)255;
        return p;
    };
    ushort* xbb     = (ushort*)carve((size_t)NN * 256 * 2);   // bf16(x)
    ushort* x_srcb  = (ushort*)carve((size_t)NN * 256 * 2);   // bf16 x_src
    ushort* hb      = (ushort*)carve((size_t)NN * 256 * 2);   // bf16 h (layer1 out)
    float* s_src    = (float*)carve((size_t)NN * 16 * 4);
    float* s_dst    = (float*)carve((size_t)NN * 16 * 4);
    float* sedge    = (float*)carve((size_t)NE * 4 * 4);
    int*   cnt      = (int*)carve((size_t)(2 * NN) * 4);
    int*   cursor   = cnt + NN;
    int*   row_ptr  = (int*)carve((size_t)(NN + 1) * 4);
    int*   perm     = (int*)carve((size_t)NE * 4);
    int*   node_perm= (int*)carve((size_t)NN * 4);
    int*   ntoff    = (int*)carve(4 * 4);
    int*   blks     = (int*)carve((size_t)(4 * NBLK) * 4);
    float* u1       = (float*)carve(12288 * 4);
    float* u2       = (float*)carve(12288 * 4);
    float* v1       = (float*)carve(512 * 4);
    float* v2       = (float*)carve(512 * 4);
    ushort* Wt1     = (ushort*)carve((size_t)196608 * 2);
    ushort* Wt2     = (ushort*)carve((size_t)196608 * 2);
    if (off > ws_size) return;

    const int* srca = ei;
    const int* dsta = ei + NE;

    hipMemsetAsync(cnt, 0, (size_t)(2 * NN) * 4, stream);

    convert_k<<<(NN * 64 + 255) / 256, 256, 0, stream>>>(x, xbb);
    prep_fold<<<100, 256, 0, stream>>>(W_dst1, att_dst1, W_edge1, att_edge1,
                                       W_dst2, att_dst2, W_edge2, att_edge2,
                                       u1, u2, v1, v2);
    prep_wt<<<1536, 256, 0, stream>>>(W_src1, W_src2, Wt1, Wt2);
    hist_k<<<(NE + 255) / 256, 256, 0, stream>>>(dsta, cnt);
    csr_blocksum<<<NBLK, 256, 0, stream>>>(cnt, ntype, blks);
    csr_scanmid<<<1, 256, 0, stream>>>(blks, ntoff);
    csr_apply<<<NBLK, 256, 0, stream>>>(cnt, ntype, blks, ntoff, row_ptr, node_perm);
    scatter_k<<<(NE + 255) / 256, 256, 0, stream>>>(dsta, row_ptr, cursor, perm);

    dim3 ggrid((NN + GROWS - 1) / GROWS, 256 / GNCH, NTY);

    // ---- layer 1
    gemm_bf16<<<ggrid, 256, 0, stream>>>(xbb, Wt1, node_perm, ntoff, x_srcb);
    scores_k<<<NN / 4, 256, 0, stream>>>(x_srcb, xbb, att_src1, u1, ntype, s_src, s_dst);
    sedge_k<<<(NE + 255) / 256, 256, 0, stream>>>(eattr, etype, v1, sedge);
    aggregate_k<<<NN / 4, 256, 0, stream>>>(x_srcb, s_src, s_dst, sedge, row_ptr, perm,
                                            srca, etype, bias1, gamma1, beta1, hb, 1);

    // ---- layer 2
    gemm_bf16<<<ggrid, 256, 0, stream>>>(hb, Wt2, node_perm, ntoff, x_srcb);
    scores_k<<<NN / 4, 256, 0, stream>>>(x_srcb, hb, att_src2, u2, ntype, s_src, s_dst);
    sedge_k<<<(NE + 255) / 256, 256, 0, stream>>>(eattr, etype, v2, sedge);
    aggregate_k<<<NN / 4, 256, 0, stream>>>(x_srcb, s_src, s_dst, sedge, row_ptr, perm,
                                            srca, etype, bias2, nullptr, nullptr,
                                            d_out, 2);
}

// Round 5
// 521.859 us; speedup vs baseline: 2.5535x; 1.0427x over previous
//
#include <hip/hip_runtime.h>

#define NN 50000
#define NE 400000
#define NH 4
#define NTY 3
#define ETY 4
#define EDIM 32
#define NBLK 196   // ceil(NN/256)

typedef __attribute__((ext_vector_type(8))) short bf16x8;
typedef __attribute__((ext_vector_type(4))) float f32x4;

static __device__ __forceinline__ unsigned short f2bf(float f) {
    unsigned u = __float_as_uint(f);
    unsigned r = (u + 0x7FFFu + ((u >> 16) & 1u)) >> 16;   // RNE
    return (unsigned short)r;
}
static __device__ __forceinline__ float bf2f(unsigned short s) {
    return __uint_as_float(((unsigned)s) << 16);
}

// ---------------------------------------------------------------- convert x -> bf16
__global__ __launch_bounds__(256) void convert_k(const float* __restrict__ x,
                                                 ushort* __restrict__ xb)
{
    int i = blockIdx.x * 256 + threadIdx.x;          // one float4 per thread
    if (i >= NN * 64) return;
    float4 v = ((const float4*)x)[i];
    ushort4 o;
    o.x = f2bf(v.x); o.y = f2bf(v.y); o.z = f2bf(v.z); o.w = f2bf(v.w);
    ((ushort4*)xb)[i] = o;
}

// ---------------------------------------------------------------- prep: fold u,v
__global__ __launch_bounds__(256) void prep_fold(
    const float* __restrict__ W_dst1, const float* __restrict__ att_dst1,
    const float* __restrict__ W_edge1, const float* __restrict__ att_edge1,
    const float* __restrict__ W_dst2, const float* __restrict__ att_dst2,
    const float* __restrict__ W_edge2, const float* __restrict__ att_edge2,
    float* __restrict__ u1, float* __restrict__ u2,
    float* __restrict__ v1, float* __restrict__ v2)
{
    int idx = blockIdx.x * 256 + threadIdx.x;   // 25600 total
    if (idx < 24576) {
        const float* W; const float* A; float* U; int i;
        if (idx < 12288) { W = W_dst1; A = att_dst1; U = u1; i = idx; }
        else             { W = W_dst2; A = att_dst2; U = u2; i = idx - 12288; }
        int d = i & 255, h = (i >> 8) & 3, t = (i >> 10) & 3, tn = i >> 12;
        const float* wp = W + tn * 65536 + d * 256 + h * 64;
        const float* ap = A + t * 256 + h * 64;
        float s = 0.f;
        #pragma unroll 8
        for (int c = 0; c < 64; ++c) s += wp[c] * ap[c];
        U[(tn * 16 + t * 4 + h) * 256 + d] = s;
    } else {
        int i = idx - 24576;
        const float* W; const float* A; float* V;
        if (i < 512) { W = W_edge1; A = att_edge1; V = v1; }
        else         { W = W_edge2; A = att_edge2; V = v2; i -= 512; }
        int d = i & 31, h = (i >> 5) & 3, t = i >> 7;
        const float* wp = W + t * (EDIM * 256) + d * 256 + h * 64;
        const float* ap = A + t * 256 + h * 64;
        float s = 0.f;
        #pragma unroll 8
        for (int c = 0; c < 64; ++c) s += wp[c] * ap[c];
        V[(t * 4 + h) * 32 + d] = s;
    }
}

// ---------------------------------------------------------------- prep: Wt bf16
__global__ __launch_bounds__(256) void prep_wt(
    const float* __restrict__ W1, const float* __restrict__ W2,
    ushort* __restrict__ Wt1, ushort* __restrict__ Wt2)
{
    int idx = blockIdx.x * 256 + threadIdx.x;   // 393216 total
    const int HALF = 196608;
    const float* W = (idx < HALF) ? W1 : W2;
    ushort* O = (idx < HALF) ? Wt1 : Wt2;
    int i = (idx < HALF) ? idx : idx - HALF;
    int n = i & 255, k = (i >> 8) & 255, t = i >> 16;
    O[t * 65536 + n * 256 + k] = f2bf(W[t * 65536 + k * 256 + n]);
}

// ---------------------------------------------------------------- CSR build
__global__ void hist_k(const int* __restrict__ dst, int* __restrict__ cnt)
{
    int i = blockIdx.x * 256 + threadIdx.x;
    if (i < NE) atomicAdd(&cnt[dst[i]], 1);
}

__global__ __launch_bounds__(256) void csr_blocksum(
    const int* __restrict__ cnt, const int* __restrict__ ntype,
    int* __restrict__ blks)  // [4][NBLK]
{
    int tid = threadIdx.x, b = blockIdx.x;
    int j = b * 256 + tid;
    int c = (j < NN) ? cnt[j] : 0;
    int t = (j < NN) ? ntype[j] : 3;
    int p = (t < 3) ? (1 << (t * 10)) : 0;
    #pragma unroll
    for (int d = 1; d < 64; d <<= 1) { c += __shfl_xor(c, d); p += __shfl_xor(p, d); }
    __shared__ int ws[2][4];
    int lane = tid & 63, w = tid >> 6;
    if (lane == 0) { ws[0][w] = c; ws[1][w] = p; }
    __syncthreads();
    if (tid == 0) {
        int C = ws[0][0] + ws[0][1] + ws[0][2] + ws[0][3];
        int P = ws[1][0] + ws[1][1] + ws[1][2] + ws[1][3];
        blks[b]            = C;
        blks[NBLK + b]     = P & 1023;
        blks[2 * NBLK + b] = (P >> 10) & 1023;
        blks[3 * NBLK + b] = (P >> 20) & 1023;
    }
}

__global__ __launch_bounds__(256) void csr_scanmid(int* __restrict__ blks,
                                                   int* __restrict__ ntoff)
{
    __shared__ int4 part[256];
    int tid = threadIdx.x;
    int4 v = make_int4(0, 0, 0, 0);
    if (tid < NBLK)
        v = make_int4(blks[tid], blks[NBLK + tid], blks[2 * NBLK + tid], blks[3 * NBLK + tid]);
    int4 orig = v;
    part[tid] = v;
    __syncthreads();
    for (int off = 1; off < 256; off <<= 1) {
        int4 u = (tid >= off) ? part[tid - off] : make_int4(0, 0, 0, 0);
        __syncthreads();
        part[tid].x += u.x; part[tid].y += u.y; part[tid].z += u.z; part[tid].w += u.w;
        __syncthreads();
    }
    int4 inc = part[tid];
    if (tid < NBLK) {
        blks[tid]            = inc.x - orig.x;
        blks[NBLK + tid]     = inc.y - orig.y;
        blks[2 * NBLK + tid] = inc.z - orig.z;
        blks[3 * NBLK + tid] = inc.w - orig.w;
    }
    if (tid == 255) {
        ntoff[0] = 0; ntoff[1] = inc.y; ntoff[2] = inc.y + inc.z;
        ntoff[3] = inc.y + inc.z + inc.w;
    }
}

__global__ __launch_bounds__(256) void csr_apply(
    const int* __restrict__ cnt, const int* __restrict__ ntype,
    const int* __restrict__ blks, const int* __restrict__ ntoff,
    int* __restrict__ row_ptr, int* __restrict__ node_perm)
{
    int tid = threadIdx.x, b = blockIdx.x;
    int j = b * 256 + tid;
    int c = (j < NN) ? cnt[j] : 0;
    int t = (j < NN) ? ntype[j] : 3;
    int p = (t < 3) ? (1 << (t * 10)) : 0;
    int lane = tid & 63, w = tid >> 6;
    int ic = c, ip = p;
    #pragma unroll
    for (int d = 1; d < 64; d <<= 1) {
        int uc = __shfl_up(ic, d), up = __shfl_up(ip, d);
        if (lane >= d) { ic += uc; ip += up; }
    }
    __shared__ int ws[2][4];
    if (lane == 63) { ws[0][w] = ic; ws[1][w] = ip; }
    __syncthreads();
    int coff = 0, poff = 0;
    for (int i = 0; i < w; ++i) { coff += ws[0][i]; poff += ws[1][i]; }
    int exc  = ic - c + coff;
    int expp = ip - p + poff;
    if (j < NN) {
        row_ptr[j] = blks[b] + exc;
        if (t < 3) {
            int tb   = blks[(t + 1) * NBLK + b];
            int tpfx = (expp >> (t * 10)) & 1023;
            node_perm[ntoff[t] + tb + tpfx] = j;
        }
    }
    if (j == 0) row_ptr[NN] = NE;
}

__global__ void scatter_k(const int* __restrict__ dst,
                          const int* __restrict__ row_ptr, int* __restrict__ cursor,
                          int* __restrict__ perm)
{
    int i = blockIdx.x * 256 + threadIdx.x;
    if (i < NE) {
        int d = dst[i];
        int pos = row_ptr[d] + atomicAdd(&cursor[d], 1);
        perm[pos] = i;
    }
}

// ---------------------------------------------------------------- bf16 MFMA GEMM
#define GROWS 64
#define GNCH 64
__global__ __launch_bounds__(256) void gemm_bf16(
    const ushort* __restrict__ xb, const ushort* __restrict__ Wtb,
    const int* __restrict__ node_perm, const int* __restrict__ ntoff,
    ushort* __restrict__ xout)
{
    int t = blockIdx.z;
    int seg0 = ntoff[t], seg1 = ntoff[t + 1];
    int row0 = seg0 + blockIdx.x * GROWS;
    if (row0 >= seg1) return;
    int nb = blockIdx.y * GNCH;

    __shared__ __align__(16) ushort Xl[GROWS * 256];  // 32 KB
    __shared__ __align__(16) ushort Wl[GNCH * 256];   // 32 KB

    int tid = threadIdx.x;
    int w = tid >> 6, l = tid & 63;
    int lhalf = l >> 5;
    int kb = (l & 31) * 16;                 // byte offset within a 512B row
    const ushort* wsrc = Wtb + (size_t)t * 65536;

    #pragma unroll
    for (int it = 0; it < 8; ++it) {
        int row = w * 16 + it * 2 + lhalf;  // 0..63
        int rp = row0 + row;
        int gr = (rp < seg1) ? node_perm[rp] : 0;
        uint4 xv = *(const uint4*)((const char*)(xb + (size_t)gr * 256) + kb);
        *(uint4*)((char*)Xl + row * 512 + (kb ^ ((row & 7) << 4))) = xv;
        uint4 wv = *(const uint4*)((const char*)(wsrc + (size_t)(nb + row) * 256) + kb);
        *(uint4*)((char*)Wl + row * 512 + (kb ^ ((row & 7) << 4))) = wv;
    }
    __syncthreads();

    int g = l >> 4;          // k-group 0..3
    int r16 = l & 15;

    f32x4 acc0 = {0.f, 0.f, 0.f, 0.f}, acc1 = acc0, acc2 = acc0, acc3 = acc0;
    int wrow = w * 16 + r16;
    const char* wbase = (const char*)Wl + wrow * 512;
    int wsw = (wrow & 7) << 4;

    #pragma unroll
    for (int ks = 0; ks < 8; ++ks) {
        int kbyte = ks * 64 + g * 16;
        bf16x8 a = *(const bf16x8*)(wbase + (kbyte ^ wsw));
        bf16x8 b0 = *(const bf16x8*)((const char*)Xl + (0 * 16 + r16) * 512 + (kbyte ^ ((r16 & 7) << 4)));
        bf16x8 b1 = *(const bf16x8*)((const char*)Xl + (16 + r16) * 512 + (kbyte ^ (((16 + r16) & 7) << 4)));
        bf16x8 b2 = *(const bf16x8*)((const char*)Xl + (32 + r16) * 512 + (kbyte ^ (((32 + r16) & 7) << 4)));
        bf16x8 b3 = *(const bf16x8*)((const char*)Xl + (48 + r16) * 512 + (kbyte ^ (((48 + r16) & 7) << 4)));
        acc0 = __builtin_amdgcn_mfma_f32_16x16x32_bf16(a, b0, acc0, 0, 0, 0);
        acc1 = __builtin_amdgcn_mfma_f32_16x16x32_bf16(a, b1, acc1, 0, 0, 0);
        acc2 = __builtin_amdgcn_mfma_f32_16x16x32_bf16(a, b2, acc2, 0, 0, 0);
        acc3 = __builtin_amdgcn_mfma_f32_16x16x32_bf16(a, b3, acc3, 0, 0, 0);
    }

    int n = nb + w * 16 + g * 4;            // 4 consecutive channels per lane
    f32x4 aa[4] = {acc0, acc1, acc2, acc3};
    #pragma unroll
    for (int fr = 0; fr < 4; ++fr) {
        int rp = row0 + fr * 16 + r16;
        if (rp < seg1) {
            int gr = node_perm[rp];
            ushort4 o;
            o.x = f2bf(aa[fr][0]); o.y = f2bf(aa[fr][1]);
            o.z = f2bf(aa[fr][2]); o.w = f2bf(aa[fr][3]);
            *(ushort4*)(xout + (size_t)gr * 256 + n) = o;
        }
    }
}

// ---------------------------------------------------------------- scores
__global__ __launch_bounds__(256) void scores_k(
    const ushort* __restrict__ xsb, const ushort* __restrict__ xib,
    const float* __restrict__ att_src, const float* __restrict__ u,
    const int* __restrict__ ntype,
    float* __restrict__ s_src, float* __restrict__ s_dst)
{
    int n = blockIdx.x * 4 + (threadIdx.x >> 6);
    int lane = threadIdx.x & 63;
    ushort4 q4 = *(const ushort4*)(xsb + (size_t)n * 256 + lane * 4);
    ushort4 i4 = *(const ushort4*)(xib + (size_t)n * 256 + lane * 4);
    float xs0 = bf2f(q4.x), xs1 = bf2f(q4.y), xs2 = bf2f(q4.z), xs3 = bf2f(q4.w);
    float xi0 = bf2f(i4.x), xi1 = bf2f(i4.y), xi2 = bf2f(i4.z), xi3 = bf2f(i4.w);
    int tn = ntype[n];
    int h = lane >> 4;
    #pragma unroll
    for (int t = 0; t < 4; ++t) {
        float4 a = *(const float4*)(att_src + t * 256 + lane * 4);
        float p = xs0 * a.x + xs1 * a.y + xs2 * a.z + xs3 * a.w;
        p += __shfl_xor(p, 1); p += __shfl_xor(p, 2);
        p += __shfl_xor(p, 4); p += __shfl_xor(p, 8);
        if ((lane & 15) == 0) s_src[(size_t)n * 16 + t * 4 + h] = p;
    }
    #pragma unroll
    for (int th = 0; th < 16; ++th) {
        float4 uu = *(const float4*)(u + (size_t)(tn * 16 + th) * 256 + lane * 4);
        float p = xi0 * uu.x + xi1 * uu.y + xi2 * uu.z + xi3 * uu.w;
        p += __shfl_xor(p, 1); p += __shfl_xor(p, 2); p += __shfl_xor(p, 4);
        p += __shfl_xor(p, 8); p += __shfl_xor(p, 16); p += __shfl_xor(p, 32);
        if (lane == 0) s_dst[(size_t)n * 16 + th] = p;
    }
}

// ---------------------------------------------------------------- edge scores (both layers)
__global__ void sedge2_k(const float* __restrict__ eattr, const int* __restrict__ etype,
                         const float* __restrict__ v1, const float* __restrict__ v2,
                         float* __restrict__ sedge1, float* __restrict__ sedge2)
{
    int e = blockIdx.x * 256 + threadIdx.x;
    if (e >= NE) return;
    int t = etype[e];
    float4 ea[8];
    #pragma unroll
    for (int i = 0; i < 8; ++i) ea[i] = *(const float4*)(eattr + (size_t)e * 32 + i * 4);
    #pragma unroll
    for (int h = 0; h < 4; ++h) {
        const float* vp1 = v1 + (t * 4 + h) * 32;
        const float* vp2 = v2 + (t * 4 + h) * 32;
        float s1 = 0.f, s2 = 0.f;
        #pragma unroll
        for (int i = 0; i < 8; ++i) {
            float4 w1 = *(const float4*)(vp1 + i * 4);
            float4 w2 = *(const float4*)(vp2 + i * 4);
            s1 += ea[i].x * w1.x + ea[i].y * w1.y + ea[i].z * w1.z + ea[i].w * w1.w;
            s2 += ea[i].x * w2.x + ea[i].y * w2.y + ea[i].z * w2.z + ea[i].w * w2.w;
        }
        sedge1[(size_t)e * 4 + h] = s1;
        sedge2[(size_t)e * 4 + h] = s2;
    }
}

// ---------------------------------------------------------------- attention weights
// Wave per dst node, lane per CSR slot: alpha -> leaky -> wave softmax ->
// normalized w_csr[i][4] + src_csr[i], both written in CSR order (coalesced).
static __device__ __forceinline__ float4 alpha_slot(
    int k, int n, const int* __restrict__ perm, const int* __restrict__ srca,
    const int* __restrict__ etype, const float* __restrict__ s_src,
    const float* __restrict__ s_dst, const float* __restrict__ sedge, int* sOut)
{
    int e = perm[k];
    int s = srca[e];
    int t = etype[e];
    float4 ss = *(const float4*)(s_src + (size_t)s * 16 + t * 4);
    float4 sd = *(const float4*)(s_dst + (size_t)n * 16 + t * 4);
    float4 se = *(const float4*)(sedge + (size_t)e * 4);
    float4 a;
    a.x = ss.x + sd.x + se.x; a.x = (a.x >= 0.f) ? a.x : 0.2f * a.x;
    a.y = ss.y + sd.y + se.y; a.y = (a.y >= 0.f) ? a.y : 0.2f * a.y;
    a.z = ss.z + sd.z + se.z; a.z = (a.z >= 0.f) ? a.z : 0.2f * a.z;
    a.w = ss.w + sd.w + se.w; a.w = (a.w >= 0.f) ? a.w : 0.2f * a.w;
    *sOut = s;
    return a;
}

__global__ __launch_bounds__(256) void wgt_k(
    const int* __restrict__ row_ptr, const int* __restrict__ perm,
    const int* __restrict__ srca, const int* __restrict__ etype,
    const float* __restrict__ s_src, const float* __restrict__ s_dst,
    const float* __restrict__ sedge,
    float* __restrict__ w_csr, int* __restrict__ src_csr)
{
    int n = blockIdx.x * 4 + (threadIdx.x >> 6);
    int lane = threadIdx.x & 63;
    int beg = row_ptr[n], end = row_ptr[n + 1];
    int k0 = beg + lane;
    bool act = k0 < end;
    int sF = 0;
    float4 aF = make_float4(-1e30f, -1e30f, -1e30f, -1e30f);
    if (act) aF = alpha_slot(k0, n, perm, srca, etype, s_src, s_dst, sedge, &sF);

    float4 mx = aF;
    for (int k = k0 + 64; k < end; k += 64) {   // deg > 64: vanishingly rare
        int s2; float4 t = alpha_slot(k, n, perm, srca, etype, s_src, s_dst, sedge, &s2);
        mx.x = fmaxf(mx.x, t.x); mx.y = fmaxf(mx.y, t.y);
        mx.z = fmaxf(mx.z, t.z); mx.w = fmaxf(mx.w, t.w);
    }
    #pragma unroll
    for (int d = 1; d < 64; d <<= 1) {
        mx.x = fmaxf(mx.x, __shfl_xor(mx.x, d));
        mx.y = fmaxf(mx.y, __shfl_xor(mx.y, d));
        mx.z = fmaxf(mx.z, __shfl_xor(mx.z, d));
        mx.w = fmaxf(mx.w, __shfl_xor(mx.w, d));
    }
    float4 ex = make_float4(0.f, 0.f, 0.f, 0.f);
    if (act) {
        ex.x = __expf(aF.x - mx.x); ex.y = __expf(aF.y - mx.y);
        ex.z = __expf(aF.z - mx.z); ex.w = __expf(aF.w - mx.w);
    }
    float4 sm = ex;
    for (int k = k0 + 64; k < end; k += 64) {
        int s2; float4 t = alpha_slot(k, n, perm, srca, etype, s_src, s_dst, sedge, &s2);
        sm.x += __expf(t.x - mx.x); sm.y += __expf(t.y - mx.y);
        sm.z += __expf(t.z - mx.z); sm.w += __expf(t.w - mx.w);
    }
    #pragma unroll
    for (int d = 1; d < 64; d <<= 1) {
        sm.x += __shfl_xor(sm.x, d); sm.y += __shfl_xor(sm.y, d);
        sm.z += __shfl_xor(sm.z, d); sm.w += __shfl_xor(sm.w, d);
    }
    float4 inv;
    inv.x = 1.f / (sm.x + 1e-16f); inv.y = 1.f / (sm.y + 1e-16f);
    inv.z = 1.f / (sm.z + 1e-16f); inv.w = 1.f / (sm.w + 1e-16f);
    if (act) {
        float4 o = make_float4(ex.x * inv.x, ex.y * inv.y, ex.z * inv.z, ex.w * inv.w);
        *(float4*)(w_csr + (size_t)k0 * 4) = o;
        src_csr[k0] = sF;
    }
    for (int k = k0 + 64; k < end; k += 64) {
        int s2; float4 t = alpha_slot(k, n, perm, srca, etype, s_src, s_dst, sedge, &s2);
        float4 o = make_float4(__expf(t.x - mx.x) * inv.x, __expf(t.y - mx.y) * inv.y,
                               __expf(t.z - mx.z) * inv.z, __expf(t.w - mx.w) * inv.w);
        *(float4*)(w_csr + (size_t)k * 4) = o;
        src_csr[k] = s2;
    }
}

// ---------------------------------------------------------------- aggregate
// Wave per dst node: acc += w * row. No softmax in the loop -> loads pipeline.
//   mode 1: +bias, LayerNorm, ELU  -> bf16 h (N,256)
//   mode 2: mean over heads +bias  -> f32 out (N,64)
__global__ __launch_bounds__(256) void aggregate_k(
    const ushort* __restrict__ xsb, const float* __restrict__ w_csr,
    const int* __restrict__ src_csr, const int* __restrict__ row_ptr,
    const float* __restrict__ bias, const float* __restrict__ gamma,
    const float* __restrict__ beta, void* __restrict__ out, int mode)
{
    int n = blockIdx.x * 4 + (threadIdx.x >> 6);
    int lane = threadIdx.x & 63;
    int h2 = lane >> 4;
    int beg = row_ptr[n], end = row_ptr[n + 1];

    float4 acc = make_float4(0.f, 0.f, 0.f, 0.f);
    for (int i = beg; i < end; ++i) {
        float wv = w_csr[(size_t)i * 4 + h2];
        int s = src_csr[i];
        ushort4 xv = *(const ushort4*)(xsb + (size_t)s * 256 + lane * 4);
        acc.x += wv * bf2f(xv.x);
        acc.y += wv * bf2f(xv.y);
        acc.z += wv * bf2f(xv.z);
        acc.w += wv * bf2f(xv.w);
    }

    if (mode == 1) {
        float4 bb = *(const float4*)(bias + lane * 4);
        float vals[4] = { acc.x + bb.x, acc.y + bb.y, acc.z + bb.z, acc.w + bb.w };
        float s = vals[0] + vals[1] + vals[2] + vals[3];
        s += __shfl_xor(s, 1); s += __shfl_xor(s, 2); s += __shfl_xor(s, 4);
        s += __shfl_xor(s, 8); s += __shfl_xor(s, 16); s += __shfl_xor(s, 32);
        float mu = s * (1.f / 256.f);
        float q = 0.f;
        #pragma unroll
        for (int j = 0; j < 4; ++j) { float d = vals[j] - mu; q += d * d; }
        q += __shfl_xor(q, 1); q += __shfl_xor(q, 2); q += __shfl_xor(q, 4);
        q += __shfl_xor(q, 8); q += __shfl_xor(q, 16); q += __shfl_xor(q, 32);
        float r = rsqrtf(q * (1.f / 256.f) + 1e-5f);
        float4 gg = *(const float4*)(gamma + lane * 4);
        float4 be = *(const float4*)(beta + lane * 4);
        ushort4 o; float y;
        y = (vals[0] - mu) * r * gg.x + be.x; o.x = f2bf((y > 0.f) ? y : (__expf(y) - 1.f));
        y = (vals[1] - mu) * r * gg.y + be.y; o.y = f2bf((y > 0.f) ? y : (__expf(y) - 1.f));
        y = (vals[2] - mu) * r * gg.z + be.z; o.z = f2bf((y > 0.f) ? y : (__expf(y) - 1.f));
        y = (vals[3] - mu) * r * gg.w + be.w; o.w = f2bf((y > 0.f) ? y : (__expf(y) - 1.f));
        *(ushort4*)((ushort*)out + (size_t)n * 256 + lane * 4) = o;
    } else {
        acc.x += __shfl_xor(acc.x, 16); acc.x += __shfl_xor(acc.x, 32);
        acc.y += __shfl_xor(acc.y, 16); acc.y += __shfl_xor(acc.y, 32);
        acc.z += __shfl_xor(acc.z, 16); acc.z += __shfl_xor(acc.z, 32);
        acc.w += __shfl_xor(acc.w, 16); acc.w += __shfl_xor(acc.w, 32);
        if (lane < 16) {
            float4 bb = *(const float4*)(bias + lane * 4);
            float4 o;
            o.x = acc.x * 0.25f + bb.x;
            o.y = acc.y * 0.25f + bb.y;
            o.z = acc.z * 0.25f + bb.z;
            o.w = acc.w * 0.25f + bb.w;
            *(float4*)((float*)out + (size_t)n * 64 + lane * 4) = o;
        }
    }
}

// ---------------------------------------------------------------- launch
extern "C" void kernel_launch(void* const* d_in, const int* in_sizes, int n_in,
                              void* d_out, int out_size, void* d_ws, size_t ws_size,
                              hipStream_t stream)
{
    (void)in_sizes; (void)n_in; (void)out_size;
    const float* x        = (const float*)d_in[0];
    const int*   ei       = (const int*)d_in[1];
    const int*   ntype    = (const int*)d_in[2];
    const int*   etype    = (const int*)d_in[3];
    const float* eattr    = (const float*)d_in[4];
    const float* W_src1   = (const float*)d_in[5];
    const float* W_dst1   = (const float*)d_in[6];
    const float* att_src1 = (const float*)d_in[7];
    const float* att_dst1 = (const float*)d_in[8];
    const float* W_edge1  = (const float*)d_in[9];
    const float* att_edge1= (const float*)d_in[10];
    const float* bias1    = (const float*)d_in[11];
    const float* gamma1   = (const float*)d_in[12];
    const float* beta1    = (const float*)d_in[13];
    const float* W_src2   = (const float*)d_in[14];
    const float* W_dst2   = (const float*)d_in[15];
    const float* att_src2 = (const float*)d_in[16];
    const float* att_dst2 = (const float*)d_in[17];
    const float* W_edge2  = (const float*)d_in[18];
    const float* att_edge2= (const float*)d_in[19];
    const float* bias2    = (const float*)d_in[20];

    char* w = (char*)d_ws;
    size_t off = 0;
    auto carve = [&](size_t bytes) -> char* {
        char* p = w + off;
        off = (off + bytes + 255) & ~(size_t)255;
        return p;
    };
    ushort* xbb     = (ushort*)carve((size_t)NN * 256 * 2);   // bf16(x)
    ushort* x_srcb  = (ushort*)carve((size_t)NN * 256 * 2);   // bf16 x_src
    ushort* hb      = (ushort*)carve((size_t)NN * 256 * 2);   // bf16 h (layer1 out)
    float* s_src    = (float*)carve((size_t)NN * 16 * 4);
    float* s_dst    = (float*)carve((size_t)NN * 16 * 4);
    float* sedge1   = (float*)carve((size_t)NE * 4 * 4);
    float* sedge2   = (float*)carve((size_t)NE * 4 * 4);
    float* w_csr    = (float*)carve((size_t)NE * 4 * 4);
    int*   src_csr  = (int*)carve((size_t)NE * 4);
    int*   cnt      = (int*)carve((size_t)(2 * NN) * 4);
    int*   cursor   = cnt + NN;
    int*   row_ptr  = (int*)carve((size_t)(NN + 1) * 4);
    int*   perm     = (int*)carve((size_t)NE * 4);
    int*   node_perm= (int*)carve((size_t)NN * 4);
    int*   ntoff    = (int*)carve(4 * 4);
    int*   blks     = (int*)carve((size_t)(4 * NBLK) * 4);
    float* u1       = (float*)carve(12288 * 4);
    float* u2       = (float*)carve(12288 * 4);
    float* v1       = (float*)carve(512 * 4);
    float* v2       = (float*)carve(512 * 4);
    ushort* Wt1     = (ushort*)carve((size_t)196608 * 2);
    ushort* Wt2     = (ushort*)carve((size_t)196608 * 2);
    if (off > ws_size) return;

    const int* srca = ei;
    const int* dsta = ei + NE;

    hipMemsetAsync(cnt, 0, (size_t)(2 * NN) * 4, stream);

    convert_k<<<(NN * 64 + 255) / 256, 256, 0, stream>>>(x, xbb);
    prep_fold<<<100, 256, 0, stream>>>(W_dst1, att_dst1, W_edge1, att_edge1,
                                       W_dst2, att_dst2, W_edge2, att_edge2,
                                       u1, u2, v1, v2);
    prep_wt<<<1536, 256, 0, stream>>>(W_src1, W_src2, Wt1, Wt2);
    hist_k<<<(NE + 255) / 256, 256, 0, stream>>>(dsta, cnt);
    csr_blocksum<<<NBLK, 256, 0, stream>>>(cnt, ntype, blks);
    csr_scanmid<<<1, 256, 0, stream>>>(blks, ntoff);
    csr_apply<<<NBLK, 256, 0, stream>>>(cnt, ntype, blks, ntoff, row_ptr, node_perm);
    scatter_k<<<(NE + 255) / 256, 256, 0, stream>>>(dsta, row_ptr, cursor, perm);
    sedge2_k<<<(NE + 255) / 256, 256, 0, stream>>>(eattr, etype, v1, v2, sedge1, sedge2);

    dim3 ggrid((NN + GROWS - 1) / GROWS, 256 / GNCH, NTY);

    // ---- layer 1
    gemm_bf16<<<ggrid, 256, 0, stream>>>(xbb, Wt1, node_perm, ntoff, x_srcb);
    scores_k<<<NN / 4, 256, 0, stream>>>(x_srcb, xbb, att_src1, u1, ntype, s_src, s_dst);
    wgt_k<<<NN / 4, 256, 0, stream>>>(row_ptr, perm, srca, etype, s_src, s_dst,
                                      sedge1, w_csr, src_csr);
    aggregate_k<<<NN / 4, 256, 0, stream>>>(x_srcb, w_csr, src_csr, row_ptr,
                                            bias1, gamma1, beta1, hb, 1);

    // ---- layer 2
    gemm_bf16<<<ggrid, 256, 0, stream>>>(hb, Wt2, node_perm, ntoff, x_srcb);
    scores_k<<<NN / 4, 256, 0, stream>>>(x_srcb, hb, att_src2, u2, ntype, s_src, s_dst);
    wgt_k<<<NN / 4, 256, 0, stream>>>(row_ptr, perm, srca, etype, s_src, s_dst,
                                      sedge2, w_csr, src_csr);
    aggregate_k<<<NN / 4, 256, 0, stream>>>(x_srcb, w_csr, src_csr, row_ptr,
                                            bias2, nullptr, nullptr, d_out, 2);
}